// Round 7
// baseline (2129.467 us; speedup 1.0000x reference)
//
#include <hip/hip_runtime.h>
#include <hip/hip_bf16.h>
#include <math.h>

#define NEXP 8
#define GNUM 16
#define DH 256

typedef __attribute__((ext_vector_type(8))) short s16x8;
typedef __attribute__((ext_vector_type(4))) float f32x4;
typedef unsigned short u16;
typedef unsigned int u32;

__device__ __forceinline__ float bitsToF(u32 b){ union{u32 u; float f;} c; c.u=b; return c.f; }
__device__ __forceinline__ u16 f2bf(float f){
  union{float f; u32 u;} c; c.f=f;
  u32 r = c.u + 0x7fffu + ((c.u>>16)&1u);
  return (u16)(r>>16);
}

// global->LDS direct copy, 16B per lane. LDS dest: wave-uniform base + lane*16.
#define GLOAD_LDS16(gp, lp) __builtin_amdgcn_global_load_lds( \
    (const __attribute__((address_space(1))) unsigned int*)(gp), \
    (__attribute__((address_space(3))) unsigned int*)(lp), 16, 0, 0)

// ---------------- CSR build ----------------
__global__ void count_edges_k(const int* __restrict__ ei, const int* __restrict__ batch,
                              int* __restrict__ deg, int* __restrict__ eg, int E){
  __shared__ int leg[GNUM];
  int t = threadIdx.x;
  if (t < GNUM) leg[t] = 0;
  __syncthreads();
  int i = blockIdx.x*blockDim.x + t;
  if (i < E){
    int s = ei[i];
    int d = ei[E + i];
    atomicAdd(&deg[d], 1);
    atomicAdd(&leg[batch[s]], 1);
  }
  __syncthreads();
  if (t < GNUM){ int v = leg[t]; if (v) atomicAdd(&eg[t], v); }
}

__global__ void count_nodes_k(const int* __restrict__ batch, int* __restrict__ ng, int N){
  __shared__ int lng[GNUM];
  int t = threadIdx.x;
  if (t < GNUM) lng[t] = 0;
  __syncthreads();
  int i = blockIdx.x*blockDim.x + t;
  if (i < N) atomicAdd(&lng[batch[i]], 1);
  __syncthreads();
  if (t < GNUM){ int v = lng[t]; if (v) atomicAdd(&ng[t], v); }
}

#define SCAN_T 1024
#define SCAN_CH 32
__global__ __launch_bounds__(1024) void scan_deg_k(const int* __restrict__ deg,
    int* __restrict__ row_ptr, int* __restrict__ cursor, int N){
  __shared__ int part[SCAN_T];
  int t = threadIdx.x;
  int base = t*SCAN_CH;
  int loc[SCAN_CH];
  int s = 0;
  #pragma unroll
  for (int j=0;j<SCAN_CH;j++){
    int i = base+j;
    int v = (i<N)? deg[i] : 0;
    loc[j] = s; s += v;
  }
  part[t] = s;
  __syncthreads();
  for (int off=1; off<SCAN_T; off<<=1){
    int add = (t>=off)? part[t-off] : 0;
    __syncthreads();
    part[t] += add;
    __syncthreads();
  }
  int ex = (t==0)? 0 : part[t-1];
  #pragma unroll
  for (int j=0;j<SCAN_CH;j++){
    int i = base+j;
    if (i<N){ int v = ex + loc[j]; row_ptr[i]=v; cursor[i]=v; }
  }
  if (t == SCAN_T-1) row_ptr[N] = part[SCAN_T-1];
}

__global__ void scatter_edges_k(const int* __restrict__ ei, int* __restrict__ cursor,
                                int* __restrict__ csr_src, int E){
  int i = blockIdx.x*blockDim.x + threadIdx.x;
  if (i>=E) return;
  int s = ei[i];
  int d = ei[E + i];
  int pos = atomicAdd(&cursor[d], 1);
  csr_src[pos] = s;
}

__global__ void size_feats_k(const int* __restrict__ ng, const int* __restrict__ eg,
                             float* __restrict__ sizef){
  int g = threadIdx.x;
  if (g < GNUM){
    sizef[g*2]   = logf(fmaxf((float)ng[g], 1.f));
    sizef[g*2+1] = logf(fmaxf((float)eg[g], 1.f));
  }
}

__global__ void mark_fail_k(float* out){ out[0] = __builtin_nanf(""); }

// ---------------- encoder ----------------
__global__ __launch_bounds__(256) void encoder_k(const float* __restrict__ x,
    const float* __restrict__ W, const float* __restrict__ b,
    float* __restrict__ hf, u16* __restrict__ bh, int N){
  int n = blockIdx.x; if (n>=N) return;
  int f = threadIdx.x;
  float acc = b[f];
  #pragma unroll
  for (int k=0;k<6;k++) acc += x[n*6+k]*W[k*DH+f];
  acc = fmaxf(acc, 0.f);
  hf[(size_t)n*DH+f] = acc;
  bh[(size_t)n*DH+f] = f2bf(acc);
}

// ---------------- weight convert (coalesced, LDS transpose) ----------------
__global__ __launch_bounds__(256) void convw_k(const float* __restrict__ Wrel,
    const float* __restrict__ Wroot, u16* __restrict__ WT){
  __shared__ float tile[64][65];
  int tx = threadIdx.x;      // 0..63
  int ty = threadIdx.y;      // 0..3
  int kt = blockIdx.x & 3, ct = blockIdx.x >> 2;
  int srcRoot = blockIdx.y;
  int le = blockIdx.z;
  const float* src = (srcRoot ? Wroot : Wrel) + (size_t)le*65536;
  #pragma unroll
  for (int i=0;i<16;i++){
    int kl = ty + i*4;
    tile[kl][tx] = src[(size_t)(kt*64 + kl)*256 + ct*64 + tx];
  }
  __syncthreads();
  u16* dst = WT + (size_t)le*131072 + (srcRoot ? 256 : 0) + kt*64;
  #pragma unroll
  for (int i=0;i<16;i++){
    int cl = ty + i*4;
    dst[(size_t)(ct*64 + cl)*512 + tx] = f2bf(tile[tx][cl]);
  }
}

// ---------------- router layer 1 ----------------
#define R1N 32
__global__ __launch_bounds__(256) void router1_k(
    const float* __restrict__ hf, const float* __restrict__ sizef,
    const int* __restrict__ batch,
    const float* __restrict__ W1, const float* __restrict__ b1,
    float* __restrict__ rh, int N)
{
  __shared__ float xin[R1N][264];
  int t = threadIdx.x;
  int lane = t & 63, w = t >> 6;
  int n0 = blockIdx.x * R1N;
  #pragma unroll
  for (int i=0;i<R1N;i++){
    int n = n0 + i;
    xin[i][t] = (n<N) ? hf[(size_t)n*DH + t] : 0.f;
  }
  if (t < R1N){
    int n = n0 + t;
    int g = (n<N) ? (int)batch[n] : 0;
    xin[t][256] = sizef[g*2];
    xin[t][257] = sizef[g*2+1];
    xin[t][258] = 0.f; xin[t][259] = 0.f;
    xin[t][260] = 0.f; xin[t][261] = 0.f; xin[t][262] = 0.f; xin[t][263] = 0.f;
  }
  __syncthreads();

  int wn = w*8;
  float bb[4];
  #pragma unroll
  for (int c=0;c<4;c++) bb[c] = b1[lane + c*64];
  float acc[8][4];
  #pragma unroll
  for (int i=0;i<8;i++)
    #pragma unroll
    for (int c=0;c<4;c++) acc[i][c] = bb[c];

  #pragma unroll 2
  for (int k4=0; k4<256; k4+=4){
    float w4[4][4];
    #pragma unroll
    for (int j=0;j<4;j++)
      #pragma unroll
      for (int c=0;c<4;c++)
        w4[j][c] = W1[(size_t)(k4+j)*DH + lane + c*64];
    #pragma unroll
    for (int i=0;i<8;i++){
      f32x4 xv = *(const f32x4*)&xin[wn+i][k4];
      #pragma unroll
      for (int j=0;j<4;j++)
        #pragma unroll
        for (int c=0;c<4;c++)
          acc[i][c] += xv[j]*w4[j][c];
    }
  }
  float w256[4], w257[4];
  #pragma unroll
  for (int c=0;c<4;c++){
    w256[c] = W1[(size_t)256*DH + lane + c*64];
    w257[c] = W1[(size_t)257*DH + lane + c*64];
  }
  #pragma unroll
  for (int i=0;i<8;i++){
    float s0 = xin[wn+i][256], s1 = xin[wn+i][257];
    #pragma unroll
    for (int c=0;c<4;c++) acc[i][c] += s0*w256[c] + s1*w257[c];
  }
  #pragma unroll
  for (int i=0;i<8;i++){
    int n = n0 + wn + i;
    if (n < N){
      #pragma unroll
      for (int c=0;c<4;c++)
        rh[(size_t)n*DH + lane + c*64] = fmaxf(acc[i][c], 0.f);
    }
  }
}

// ---------------- router layer 2 + softmax + top2 ----------------
__global__ __launch_bounds__(256) void router2_k(
    const float* __restrict__ rh, const float* __restrict__ W2,
    const float* __restrict__ b2,
    int* __restrict__ ridx, float* __restrict__ rval, int N)
{
  __shared__ float w2s[NEXP][260];
  int t = threadIdx.x;
  for (int i=t; i<NEXP*DH; i+=256){
    int e = i >> 8, k = i & 255;
    w2s[e][k] = W2[(size_t)k*NEXP + e];
  }
  __syncthreads();
  int lane = t & 63, w = t >> 6;
  int n = blockIdx.x*4 + w;
  if (n >= N) return;
  const float* r = rh + (size_t)n*DH;
  float p[NEXP];
  #pragma unroll
  for (int e=0;e<NEXP;e++) p[e] = 0.f;
  #pragma unroll
  for (int c=0;c<4;c++){
    int k = lane + c*64;
    float rv = r[k];
    #pragma unroll
    for (int e=0;e<NEXP;e++) p[e] += rv * w2s[e][k];
  }
  #pragma unroll
  for (int off=1; off<64; off<<=1){
    #pragma unroll
    for (int e=0;e<NEXP;e++) p[e] += __shfl_xor(p[e], off, 64);
  }
  if (lane == 0){
    float l0[NEXP];
    #pragma unroll
    for (int e=0;e<NEXP;e++) l0[e] = p[e] + b2[e];
    float m = l0[0];
    #pragma unroll
    for (int e=1;e<NEXP;e++) m = fmaxf(m, l0[e]);
    float ex[NEXP];
    #pragma unroll
    for (int e=0;e<NEXP;e++) ex[e] = expf(l0[e]-m);
    int e0=0; float b0v=ex[0];
    #pragma unroll
    for (int e=1;e<NEXP;e++) if (ex[e]>b0v){b0v=ex[e]; e0=e;}
    int e1=(e0==0)?1:0; float b1v=ex[e1];
    #pragma unroll
    for (int e=0;e<NEXP;e++) if (e!=e0 && ex[e]>b1v){b1v=ex[e]; e1=e;}
    float sv = b0v + b1v;
    rval[n*2]   = b0v/sv;
    rval[n*2+1] = b1v/sv;
    ridx[n*2]   = e0;
    ridx[n*2+1] = e1;
  }
}

// ---------------- routing scatter: per-expert node lists ----------------
__global__ void rsort_k(const int* __restrict__ ridx, int* __restrict__ cnt,
                        int* __restrict__ plist, int* __restrict__ ppos, int N){
  int n = blockIdx.x*256 + threadIdx.x;
  if (n >= N) return;
  #pragma unroll
  for (int p2=0;p2<2;p2++){
    int e = ridx[n*2+p2];
    int pos = atomicAdd(&cnt[e], 1);
    plist[(size_t)e*N + pos] = n;
    ppos[n*2+p2] = pos;
  }
}

// ---------------- CSR aggregation (dense, batched over experts) ----------
template<int TAG>
__global__ __launch_bounds__(256) void aggregate_k(const u16* __restrict__ Hsrc,
    u16* __restrict__ Aout, const int* __restrict__ row_ptr,
    const int* __restrict__ csr_src, int N, long long srcStride){
  int e = blockIdx.y;
  const u16* H = Hsrc + (size_t)e*(size_t)srcStride;
  u16* A = Aout + (size_t)e*((size_t)N*DH);
  int node = blockIdx.x*4 + (threadIdx.x>>6);
  if (node >= N) return;
  int lane = threadIdx.x & 63;
  int beg = row_ptr[node], end = row_ptr[node+1];
  float a0=0.f,a1=0.f,a2=0.f,a3=0.f;
  const u16* Hl = H + (lane<<2);
  int i = beg;
  for (; i+8<=end; i+=8){
    int sarr[8];
    #pragma unroll
    for (int u=0;u<8;u++) sarr[u] = csr_src[i+u];
    #pragma unroll
    for (int u=0;u<8;u++){
      uint2 v = *(const uint2*)(Hl + ((size_t)sarr[u]<<8));
      a0 += bitsToF(v.x<<16);
      a1 += bitsToF(v.x & 0xffff0000u);
      a2 += bitsToF(v.y<<16);
      a3 += bitsToF(v.y & 0xffff0000u);
    }
  }
  for (; i<end; ++i){
    int s = csr_src[i];
    uint2 v = *(const uint2*)(Hl + ((size_t)s<<8));
    a0 += bitsToF(v.x<<16);
    a1 += bitsToF(v.x & 0xffff0000u);
    a2 += bitsToF(v.y<<16);
    a3 += bitsToF(v.y & 0xffff0000u);
  }
  uint2 o;
  o.x = ((u32)f2bf(a1)<<16) | f2bf(a0);
  o.y = ((u32)f2bf(a3)<<16) | f2bf(a2);
  *(uint2*)(A + ((size_t)node<<8) + (lane<<2)) = o;
}

// ---------------- sparse CSR aggregation (routed rows only, compacted) -----
__global__ __launch_bounds__(256) void agg_sparse_k(const u16* __restrict__ Hsrc,
    u16* __restrict__ Aout, const int* __restrict__ row_ptr,
    const int* __restrict__ csr_src, const int* __restrict__ plist,
    const int* __restrict__ cnt, int N){
  int e = blockIdx.y;
  int idx = blockIdx.x*4 + (threadIdx.x>>6);
  if (idx >= cnt[e]) return;
  int node = plist[(size_t)e*N + idx];
  const u16* H = Hsrc + (size_t)e*((size_t)N*DH);
  u16* A = Aout + (size_t)e*((size_t)N*DH);
  int lane = threadIdx.x & 63;
  int beg = row_ptr[node], end = row_ptr[node+1];
  float a0=0.f,a1=0.f,a2=0.f,a3=0.f;
  const u16* Hl = H + (lane<<2);
  int i = beg;
  for (; i+8<=end; i+=8){
    int sarr[8];
    #pragma unroll
    for (int u=0;u<8;u++) sarr[u] = csr_src[i+u];
    #pragma unroll
    for (int u=0;u<8;u++){
      uint2 v = *(const uint2*)(Hl + ((size_t)sarr[u]<<8));
      a0 += bitsToF(v.x<<16);
      a1 += bitsToF(v.x & 0xffff0000u);
      a2 += bitsToF(v.y<<16);
      a3 += bitsToF(v.y & 0xffff0000u);
    }
  }
  for (; i<end; ++i){
    int s = csr_src[i];
    uint2 v = *(const uint2*)(Hl + ((size_t)s<<8));
    a0 += bitsToF(v.x<<16);
    a1 += bitsToF(v.x & 0xffff0000u);
    a2 += bitsToF(v.y<<16);
    a3 += bitsToF(v.y & 0xffff0000u);
  }
  uint2 o;
  o.x = ((u32)f2bf(a1)<<16) | f2bf(a0);
  o.y = ((u32)f2bf(a3)<<16) | f2bf(a2);
  *(uint2*)(A + ((size_t)idx<<8) + (lane<<2)) = o;
}

// ---------------- bf16 MFMA GEMM (m97 structure + source-swizzled LDS) -----
// LDS slot (row,s) holds global piece p = s ^ ((row>>1)&3): the b128
// fragment read then covers all 8 bank-quads per 16-lane quarter (2-way=free).
template<int TAG>
__global__ __launch_bounds__(256,2) void gemm_k(
    const u16* __restrict__ Aagg, long long strideA,
    const u16* __restrict__ Hroot, long long strideR,
    const u16* __restrict__ WT,
    const float* __restrict__ bias,
    u16* __restrict__ Hout,
    int N, int relu_flag)
{
  __shared__ u16 As[128*32];
  __shared__ u16 Bs[128*32];
  int e = blockIdx.z;
  const u16* aBase = Aagg + (size_t)e*(size_t)strideA;
  const u16* rBase = Hroot + (size_t)e*(size_t)strideR;
  const u16* wBase = WT + (size_t)e*(256*512);
  const float* be  = bias + e*256;
  u16* Oe = Hout + (size_t)e*((size_t)N*DH);

  int tid = threadIdx.x;
  int lane = tid & 63, w = tid >> 6;
  int wr = w >> 1, wc = w & 1;
  int m0 = blockIdx.x * 128;
  int n0 = blockIdx.y * 128;

  int lrow = lane >> 2;
  int q8   = (((lane & 3) ^ ((lane >> 3) & 3))) * 8;   // swizzled source piece
  int r0 = w*16 + lrow;
  int r1 = (w+4)*16 + lrow;
  int arow0 = m0 + r0; if (arow0 >= N) arow0 = N-1;
  int arow1 = m0 + r1; if (arow1 >= N) arow1 = N-1;
  long long aoff0 = (long long)arow0*256 + q8;
  long long aoff1 = (long long)arow1*256 + q8;
  long long boff0 = (long long)(n0 + r0)*512 + q8;
  long long boff1 = (long long)(n0 + r1)*512 + q8;
  u16* aL0 = As + (size_t)w*512;
  u16* aL1 = As + (size_t)(w+4)*512;
  u16* bL0 = Bs + (size_t)w*512;
  u16* bL1 = Bs + (size_t)(w+4)*512;

  f32x4 acc[4][4];
  #pragma unroll
  for (int a=0;a<4;a++)
    #pragma unroll
    for (int b=0;b<4;b++) acc[a][b] = (f32x4){0.f,0.f,0.f,0.f};

  int fr = lane & 15;
  int fk = (((lane >> 4) ^ ((fr >> 1) & 3))) * 8;      // swizzled read piece
  const u16* aRead = As + (size_t)(wr*64 + fr)*32 + fk;
  const u16* bRead = Bs + (size_t)(wc*64 + fr)*32 + fk;

  #pragma unroll 1
  for (int half=0; half<2; ++half){
    const u16* sA = half ? rBase : aBase;
    #pragma unroll 1
    for (int kk=0; kk<8; ++kk){
      int kin = kk*32;
      int kg  = half*256 + kin;
      GLOAD_LDS16(sA + aoff0 + kin, aL0);
      GLOAD_LDS16(sA + aoff1 + kin, aL1);
      GLOAD_LDS16(wBase + boff0 + kg, bL0);
      GLOAD_LDS16(wBase + boff1 + kg, bL1);
      __syncthreads();
      s16x8 af[4], bf[4];
      #pragma unroll
      for (int mi=0;mi<4;mi++) af[mi] = *(const s16x8*)(aRead + mi*16*32);
      #pragma unroll
      for (int ni=0;ni<4;ni++) bf[ni] = *(const s16x8*)(bRead + ni*16*32);
      #pragma unroll
      for (int mi=0;mi<4;mi++)
        #pragma unroll
        for (int ni=0;ni<4;ni++)
          acc[mi][ni] = __builtin_amdgcn_mfma_f32_16x16x32_bf16(af[mi], bf[ni], acc[mi][ni], 0, 0, 0);
      __syncthreads();
    }
  }
  int fq = lane >> 4;
  #pragma unroll
  for (int ni=0;ni<4;ni++){
    int col = n0 + wc*64 + ni*16 + fr;
    float bv = be[col];
    #pragma unroll
    for (int mi=0;mi<4;mi++){
      int rowb = m0 + wr*64 + mi*16 + fq*4;
      f32x4 v = acc[mi][ni];
      #pragma unroll
      for (int j=0;j<4;j++){
        int row = rowb + j;
        if (row < N){
          float o = v[j] + bv;
          if (relu_flag) o = fmaxf(o, 0.f);
          Oe[(size_t)row*DH + col] = f2bf(o);
        }
      }
    }
  }
}

// ---------------- sparse GEMM: compacted A rows, indirect root rows --------
__global__ __launch_bounds__(256,2) void gemm_sparse_k(
    const u16* __restrict__ Aagg,   // [e][cap N][256] compacted
    const u16* __restrict__ Hroot,  // [e][N][256] dense
    const u16* __restrict__ WT,
    const float* __restrict__ bias,
    u16* __restrict__ Hout,         // [e][cap N][256] compacted
    const int* __restrict__ plist, const int* __restrict__ cnte,
    int N)
{
  __shared__ u16 As[128*32];
  __shared__ u16 Bs[128*32];
  int e = blockIdx.z;
  int cnt = cnte[e];
  int m0 = blockIdx.x * 128;
  if (m0 >= cnt) return;
  size_t NS = (size_t)N*DH;
  const u16* aBase = Aagg + (size_t)e*NS;
  const u16* rBase = Hroot + (size_t)e*NS;
  const u16* wBase = WT + (size_t)e*(256*512);
  const float* be  = bias + e*256;
  u16* Oe = Hout + (size_t)e*NS;
  const int* pl = plist + (size_t)e*N;

  int tid = threadIdx.x;
  int lane = tid & 63, w = tid >> 6;
  int wr = w >> 1, wc = w & 1;
  int n0 = blockIdx.y * 128;

  int lrow = lane >> 2;
  int q8   = (((lane & 3) ^ ((lane >> 3) & 3))) * 8;
  int r0 = w*16 + lrow;
  int r1 = (w+4)*16 + lrow;
  int ai0 = m0 + r0; if (ai0 >= cnt) ai0 = cnt-1;
  int ai1 = m0 + r1; if (ai1 >= cnt) ai1 = cnt-1;
  long long aoff0 = (long long)ai0*256 + q8;
  long long aoff1 = (long long)ai1*256 + q8;
  long long roff0 = (long long)pl[ai0]*256 + q8;
  long long roff1 = (long long)pl[ai1]*256 + q8;
  long long boff0 = (long long)(n0 + r0)*512 + q8;
  long long boff1 = (long long)(n0 + r1)*512 + q8;
  u16* aL0 = As + (size_t)w*512;
  u16* aL1 = As + (size_t)(w+4)*512;
  u16* bL0 = Bs + (size_t)w*512;
  u16* bL1 = Bs + (size_t)(w+4)*512;

  f32x4 acc[4][4];
  #pragma unroll
  for (int a=0;a<4;a++)
    #pragma unroll
    for (int b=0;b<4;b++) acc[a][b] = (f32x4){0.f,0.f,0.f,0.f};

  int fr = lane & 15;
  int fk = (((lane >> 4) ^ ((fr >> 1) & 3))) * 8;
  const u16* aRead = As + (size_t)(wr*64 + fr)*32 + fk;
  const u16* bRead = Bs + (size_t)(wc*64 + fr)*32 + fk;

  #pragma unroll 1
  for (int half=0; half<2; ++half){
    const u16* sA = half ? rBase : aBase;
    long long o0 = half ? roff0 : aoff0;
    long long o1 = half ? roff1 : aoff1;
    #pragma unroll 1
    for (int kk=0; kk<8; ++kk){
      int kin = kk*32;
      int kg  = half*256 + kin;
      GLOAD_LDS16(sA + o0 + kin, aL0);
      GLOAD_LDS16(sA + o1 + kin, aL1);
      GLOAD_LDS16(wBase + boff0 + kg, bL0);
      GLOAD_LDS16(wBase + boff1 + kg, bL1);
      __syncthreads();
      s16x8 af[4], bf[4];
      #pragma unroll
      for (int mi=0;mi<4;mi++) af[mi] = *(const s16x8*)(aRead + mi*16*32);
      #pragma unroll
      for (int ni=0;ni<4;ni++) bf[ni] = *(const s16x8*)(bRead + ni*16*32);
      #pragma unroll
      for (int mi=0;mi<4;mi++)
        #pragma unroll
        for (int ni=0;ni<4;ni++)
          acc[mi][ni] = __builtin_amdgcn_mfma_f32_16x16x32_bf16(af[mi], bf[ni], acc[mi][ni], 0, 0, 0);
      __syncthreads();
    }
  }
  int fq = lane >> 4;
  #pragma unroll
  for (int ni=0;ni<4;ni++){
    int col = n0 + wc*64 + ni*16 + fr;
    float bv = be[col];
    #pragma unroll
    for (int mi=0;mi<4;mi++){
      int rowb = m0 + wr*64 + mi*16 + fq*4;
      f32x4 v = acc[mi][ni];
      #pragma unroll
      for (int j=0;j<4;j++){
        int row = rowb + j;
        if (row < cnt){
          float o = v[j] + bv;
          Oe[(size_t)row*DH + col] = f2bf(o);
        }
      }
    }
  }
}

// ---------------- combine (sparse, indirected) ----------------
__global__ __launch_bounds__(256) void combine_sparse_k(const u16* __restrict__ H3c,
    const int* __restrict__ ridx, const int* __restrict__ ppos,
    const float* __restrict__ rval, float* __restrict__ out, int N){
  int n = blockIdx.x; if (n>=N) return;
  int f = threadIdx.x;
  int e0 = ridx[n*2], e1 = ridx[n*2+1];
  int p0 = ppos[n*2], p1 = ppos[n*2+1];
  float v0 = rval[n*2], v1 = rval[n*2+1];
  float h0 = bitsToF(((u32)H3c[((size_t)e0*N + p0)*DH + f])<<16);
  float h1 = bitsToF(((u32)H3c[((size_t)e1*N + p1)*DH + f])<<16);
  out[(size_t)n*DH + f] = v0*h0 + v1*h1;
}

// grouped dense fallback combine
__global__ __launch_bounds__(256) void combine_acc_k(const u16* __restrict__ H3,
    const int* __restrict__ ridx, const float* __restrict__ rval,
    float* __restrict__ out, int N, int eBase, int ezCnt){
  int n = blockIdx.x; if (n>=N) return;
  int f = threadIdx.x;
  size_t es = (size_t)N*DH;
  size_t off = (size_t)n*DH + f;
  float acc = out[off];
  #pragma unroll
  for (int p=0;p<2;p++){
    int e = ridx[n*2+p] - eBase;
    if (e >= 0 && e < ezCnt)
      acc += rval[n*2+p] * bitsToF(((u32)H3[(size_t)e*es + off])<<16);
  }
  out[off] = acc;
}

extern "C" void kernel_launch(void* const* d_in, const int* in_sizes, int n_in,
                              void* d_out, int out_size, void* d_ws, size_t ws_size,
                              hipStream_t stream)
{
  const float* x    = (const float*)d_in[0];
  const int*   ei   = (const int*)d_in[1];
  const int*   batch= (const int*)d_in[2];
  const float* encW = (const float*)d_in[3];
  const float* encb = (const float*)d_in[4];
  const float* rW1  = (const float*)d_in[5];
  const float* rb1  = (const float*)d_in[6];
  const float* rW2  = (const float*)d_in[7];
  const float* rb2  = (const float*)d_in[8];
  const float* Wrel = (const float*)d_in[9];
  const float* brel = (const float*)d_in[10];
  const float* Wroot= (const float*)d_in[11];
  int N = in_sizes[2];
  int E = in_sizes[1]/2;
  float* out = (float*)d_out;
  (void)n_in; (void)out_size;

  size_t NS = (size_t)N*DH;
  char* p = (char*)d_ws;
  auto carve = [&](size_t bytes)->char*{
    char* r = p; p += (bytes + 255) & ~(size_t)255; return r;
  };
  u16*  bh   = (u16*)carve(NS*2);
  u16*  WT   = (u16*)carve((size_t)3*NEXP*256*512*2);
  int*  deg  = (int*)carve((size_t)N*4 + 64*4);
  int*  ng   = deg + N;
  int*  eg   = ng + GNUM;
  int*  row_ptr = (int*)carve(((size_t)N+1)*4);
  int*  cursor  = (int*)carve((size_t)N*4);
  int*  csr     = (int*)carve((size_t)E*4);
  float* sizef  = (float*)carve(GNUM*2*4);
  int*  ridx    = (int*)carve((size_t)N*2*4);
  float* rvalv  = (float*)carve((size_t)N*2*4);
  int*  ecnt    = (int*)carve(NEXP*4);
  int*  plist   = (int*)carve((size_t)NEXP*N*4);
  int*  ppos    = (int*)carve((size_t)N*2*4);
  u16*  A0      = (u16*)carve(NS*2);
  size_t baseUsed = (size_t)(p - (char*)d_ws);

  int EZ = 0;
  for (int cand = NEXP; cand >= 1; cand >>= 1){
    if (baseUsed + (size_t)cand*3*NS*2 <= ws_size){ EZ = cand; break; }
  }
  if (EZ == 0){ mark_fail_k<<<1,1,0,stream>>>(out); return; }

  u16* Abuf = (u16*)carve((size_t)EZ*NS*2);
  u16* Hn   = (u16*)carve((size_t)EZ*NS*2);
  u16* Hc   = (u16*)carve((size_t)EZ*NS*2);
  float* hf; float* rh;
  if (EZ >= 2){ hf = (float*)Abuf; rh = (float*)Hn; }
  else {
    hf = (float*)carve(NS*4);
    rh = (float*)carve(NS*4);
    if ((size_t)(p - (char*)d_ws) > ws_size){ mark_fail_k<<<1,1,0,stream>>>(out); return; }
  }

  hipMemsetAsync(deg, 0, (size_t)N*4 + (size_t)2*GNUM*4, stream);
  hipMemsetAsync(ecnt, 0, NEXP*4, stream);
  if (EZ != NEXP) hipMemsetAsync(out, 0, NS*4, stream);

  int eb = (E + 255)/256;
  count_edges_k<<<eb, 256, 0, stream>>>(ei, batch, deg, eg, E);
  count_nodes_k<<<(N+255)/256, 256, 0, stream>>>(batch, ng, N);
  scan_deg_k<<<1, SCAN_T, 0, stream>>>(deg, row_ptr, cursor, N);
  scatter_edges_k<<<eb, 256, 0, stream>>>(ei, cursor, csr, E);
  size_feats_k<<<1, 64, 0, stream>>>(ng, eg, sizef);
  encoder_k<<<N, 256, 0, stream>>>(x, encW, encb, hf, bh, N);
  convw_k<<<dim3(16,2,3*NEXP), dim3(64,4), 0, stream>>>(Wrel, Wroot, WT);
  router1_k<<<(N+R1N-1)/R1N, 256, 0, stream>>>(hf, sizef, batch, rW1, rb1, rh, N);
  router2_k<<<(N+3)/4, 256, 0, stream>>>(rh, rW2, rb2, ridx, rvalv, N);
  rsort_k<<<(N+255)/256, 256, 0, stream>>>(ridx, ecnt, plist, ppos, N);

  int aggx = (N+3)/4;
  int mt = (N+127)/128;
  const size_t WE = (size_t)256*512;

  aggregate_k<0><<<dim3(aggx,1), 256, 0, stream>>>(bh, A0, row_ptr, csr, N, 0);

  if (EZ == NEXP){
    // dense layers 0-1, routing-sparse layer 2
    gemm_k<0><<<dim3(mt,2,NEXP), 256, 0, stream>>>(A0, 0, bh, 0,
        WT, brel, Hc, N, 1);
    aggregate_k<1><<<dim3(aggx,NEXP), 256, 0, stream>>>(Hc, Abuf, row_ptr, csr, N, (long long)NS);
    gemm_k<1><<<dim3(mt,2,NEXP), 256, 0, stream>>>(Abuf, (long long)NS, Hc, (long long)NS,
        WT + (size_t)1*NEXP*WE, brel + 1*NEXP*256, Hn, N, 1);
    agg_sparse_k<<<dim3(aggx,NEXP), 256, 0, stream>>>(Hn, Abuf, row_ptr, csr, plist, ecnt, N);
    gemm_sparse_k<<<dim3(mt,2,NEXP), 256, 0, stream>>>(Abuf, Hn,
        WT + (size_t)2*NEXP*WE, brel + 2*NEXP*256, Hc, plist, ecnt, N);
    combine_sparse_k<<<N, 256, 0, stream>>>(Hc, ridx, ppos, rvalv, out, N);
  } else {
    for (int g = 0; g < NEXP; g += EZ){
      gemm_k<0><<<dim3(mt,2,EZ), 256, 0, stream>>>(A0, 0, bh, 0,
          WT + ((size_t)0*NEXP + g)*WE, brel + (0*NEXP + g)*256, Hc, N, 1);
      aggregate_k<1><<<dim3(aggx,EZ), 256, 0, stream>>>(Hc, Abuf, row_ptr, csr, N, (long long)NS);
      gemm_k<1><<<dim3(mt,2,EZ), 256, 0, stream>>>(Abuf, (long long)NS, Hc, (long long)NS,
          WT + ((size_t)1*NEXP + g)*WE, brel + (1*NEXP + g)*256, Hn, N, 1);
      aggregate_k<2><<<dim3(aggx,EZ), 256, 0, stream>>>(Hn, Abuf, row_ptr, csr, N, (long long)NS);
      gemm_k<2><<<dim3(mt,2,EZ), 256, 0, stream>>>(Abuf, (long long)NS, Hn, (long long)NS,
          WT + ((size_t)2*NEXP + g)*WE, brel + (2*NEXP + g)*256, Hc, N, 0);
      combine_acc_k<<<N, 256, 0, stream>>>(Hc, ridx, rvalv, out, N, g, EZ);
    }
  }
}

// Round 8
// 1698.055 us; speedup vs baseline: 1.2541x; 1.2541x over previous
//
#include <hip/hip_runtime.h>
#include <hip/hip_bf16.h>
#include <math.h>

#define NEXP 8
#define GNUM 16
#define DH 256

typedef __attribute__((ext_vector_type(8))) short s16x8;
typedef __attribute__((ext_vector_type(4))) float f32x4;
typedef unsigned short u16;
typedef unsigned int u32;

__device__ __forceinline__ float bitsToF(u32 b){ union{u32 u; float f;} c; c.u=b; return c.f; }
__device__ __forceinline__ u16 f2bf(float f){
  union{float f; u32 u;} c; c.f=f;
  u32 r = c.u + 0x7fffu + ((c.u>>16)&1u);
  return (u16)(r>>16);
}

// global->LDS direct copy, 16B per lane. LDS dest: wave-uniform base + lane*16.
#define GLOAD_LDS16(gp, lp) __builtin_amdgcn_global_load_lds( \
    (const __attribute__((address_space(1))) unsigned int*)(gp), \
    (__attribute__((address_space(3))) unsigned int*)(lp), 16, 0, 0)

// ---------------- CSR build ----------------
__global__ void count_edges_k(const int* __restrict__ ei, const int* __restrict__ batch,
                              int* __restrict__ deg, int* __restrict__ eg, int E){
  __shared__ int leg[GNUM];
  int t = threadIdx.x;
  if (t < GNUM) leg[t] = 0;
  __syncthreads();
  int i = blockIdx.x*blockDim.x + t;
  if (i < E){
    int s = ei[i];
    int d = ei[E + i];
    atomicAdd(&deg[d], 1);
    atomicAdd(&leg[batch[s]], 1);
  }
  __syncthreads();
  if (t < GNUM){ int v = leg[t]; if (v) atomicAdd(&eg[t], v); }
}

__global__ void count_nodes_k(const int* __restrict__ batch, int* __restrict__ ng, int N){
  __shared__ int lng[GNUM];
  int t = threadIdx.x;
  if (t < GNUM) lng[t] = 0;
  __syncthreads();
  int i = blockIdx.x*blockDim.x + t;
  if (i < N) atomicAdd(&lng[batch[i]], 1);
  __syncthreads();
  if (t < GNUM){ int v = lng[t]; if (v) atomicAdd(&ng[t], v); }
}

#define SCAN_T 1024
#define SCAN_CH 32
__global__ __launch_bounds__(1024) void scan_deg_k(const int* __restrict__ deg,
    int* __restrict__ row_ptr, int* __restrict__ cursor, int N){
  __shared__ int part[SCAN_T];
  int t = threadIdx.x;
  int base = t*SCAN_CH;
  int loc[SCAN_CH];
  int s = 0;
  #pragma unroll
  for (int j=0;j<SCAN_CH;j++){
    int i = base+j;
    int v = (i<N)? deg[i] : 0;
    loc[j] = s; s += v;
  }
  part[t] = s;
  __syncthreads();
  for (int off=1; off<SCAN_T; off<<=1){
    int add = (t>=off)? part[t-off] : 0;
    __syncthreads();
    part[t] += add;
    __syncthreads();
  }
  int ex = (t==0)? 0 : part[t-1];
  #pragma unroll
  for (int j=0;j<SCAN_CH;j++){
    int i = base+j;
    if (i<N){ int v = ex + loc[j]; row_ptr[i]=v; cursor[i]=v; }
  }
  if (t == SCAN_T-1) row_ptr[N] = part[SCAN_T-1];
}

__global__ void scatter_edges_k(const int* __restrict__ ei, int* __restrict__ cursor,
                                int* __restrict__ csr_src, int E){
  int i = blockIdx.x*blockDim.x + threadIdx.x;
  if (i>=E) return;
  int s = ei[i];
  int d = ei[E + i];
  int pos = atomicAdd(&cursor[d], 1);
  csr_src[pos] = s;
}

__global__ void size_feats_k(const int* __restrict__ ng, const int* __restrict__ eg,
                             float* __restrict__ sizef){
  int g = threadIdx.x;
  if (g < GNUM){
    sizef[g*2]   = logf(fmaxf((float)ng[g], 1.f));
    sizef[g*2+1] = logf(fmaxf((float)eg[g], 1.f));
  }
}

__global__ void mark_fail_k(float* out){ out[0] = __builtin_nanf(""); }

// ---------------- encoder ----------------
__global__ __launch_bounds__(256) void encoder_k(const float* __restrict__ x,
    const float* __restrict__ W, const float* __restrict__ b,
    float* __restrict__ hf, u16* __restrict__ bh, int N){
  int n = blockIdx.x; if (n>=N) return;
  int f = threadIdx.x;
  float acc = b[f];
  #pragma unroll
  for (int k=0;k<6;k++) acc += x[n*6+k]*W[k*DH+f];
  acc = fmaxf(acc, 0.f);
  hf[(size_t)n*DH+f] = acc;
  bh[(size_t)n*DH+f] = f2bf(acc);
}

// ---------------- weight convert (coalesced, LDS transpose) ----------------
__global__ __launch_bounds__(256) void convw_k(const float* __restrict__ Wrel,
    const float* __restrict__ Wroot, u16* __restrict__ WT){
  __shared__ float tile[64][65];
  int tx = threadIdx.x;      // 0..63
  int ty = threadIdx.y;      // 0..3
  int kt = blockIdx.x & 3, ct = blockIdx.x >> 2;
  int srcRoot = blockIdx.y;
  int le = blockIdx.z;
  const float* src = (srcRoot ? Wroot : Wrel) + (size_t)le*65536;
  #pragma unroll
  for (int i=0;i<16;i++){
    int kl = ty + i*4;
    tile[kl][tx] = src[(size_t)(kt*64 + kl)*256 + ct*64 + tx];
  }
  __syncthreads();
  u16* dst = WT + (size_t)le*131072 + (srcRoot ? 256 : 0) + kt*64;
  #pragma unroll
  for (int i=0;i<16;i++){
    int cl = ty + i*4;
    dst[(size_t)(ct*64 + cl)*512 + tx] = f2bf(tile[tx][cl]);
  }
}

// ---------------- router layer 1 ----------------
#define R1N 32
__global__ __launch_bounds__(256) void router1_k(
    const float* __restrict__ hf, const float* __restrict__ sizef,
    const int* __restrict__ batch,
    const float* __restrict__ W1, const float* __restrict__ b1,
    float* __restrict__ rh, int N)
{
  __shared__ float xin[R1N][264];
  int t = threadIdx.x;
  int lane = t & 63, w = t >> 6;
  int n0 = blockIdx.x * R1N;
  #pragma unroll
  for (int i=0;i<R1N;i++){
    int n = n0 + i;
    xin[i][t] = (n<N) ? hf[(size_t)n*DH + t] : 0.f;
  }
  if (t < R1N){
    int n = n0 + t;
    int g = (n<N) ? (int)batch[n] : 0;
    xin[t][256] = sizef[g*2];
    xin[t][257] = sizef[g*2+1];
    xin[t][258] = 0.f; xin[t][259] = 0.f;
    xin[t][260] = 0.f; xin[t][261] = 0.f; xin[t][262] = 0.f; xin[t][263] = 0.f;
  }
  __syncthreads();

  int wn = w*8;
  float bb[4];
  #pragma unroll
  for (int c=0;c<4;c++) bb[c] = b1[lane + c*64];
  float acc[8][4];
  #pragma unroll
  for (int i=0;i<8;i++)
    #pragma unroll
    for (int c=0;c<4;c++) acc[i][c] = bb[c];

  #pragma unroll 2
  for (int k4=0; k4<256; k4+=4){
    float w4[4][4];
    #pragma unroll
    for (int j=0;j<4;j++)
      #pragma unroll
      for (int c=0;c<4;c++)
        w4[j][c] = W1[(size_t)(k4+j)*DH + lane + c*64];
    #pragma unroll
    for (int i=0;i<8;i++){
      f32x4 xv = *(const f32x4*)&xin[wn+i][k4];
      #pragma unroll
      for (int j=0;j<4;j++)
        #pragma unroll
        for (int c=0;c<4;c++)
          acc[i][c] += xv[j]*w4[j][c];
    }
  }
  float w256[4], w257[4];
  #pragma unroll
  for (int c=0;c<4;c++){
    w256[c] = W1[(size_t)256*DH + lane + c*64];
    w257[c] = W1[(size_t)257*DH + lane + c*64];
  }
  #pragma unroll
  for (int i=0;i<8;i++){
    float s0 = xin[wn+i][256], s1 = xin[wn+i][257];
    #pragma unroll
    for (int c=0;c<4;c++) acc[i][c] += s0*w256[c] + s1*w257[c];
  }
  #pragma unroll
  for (int i=0;i<8;i++){
    int n = n0 + wn + i;
    if (n < N){
      #pragma unroll
      for (int c=0;c<4;c++)
        rh[(size_t)n*DH + lane + c*64] = fmaxf(acc[i][c], 0.f);
    }
  }
}

// ---------------- router layer 2 + softmax + top2 ----------------
__global__ __launch_bounds__(256) void router2_k(
    const float* __restrict__ rh, const float* __restrict__ W2,
    const float* __restrict__ b2,
    int* __restrict__ ridx, float* __restrict__ rval, int N)
{
  __shared__ float w2s[NEXP][260];
  int t = threadIdx.x;
  for (int i=t; i<NEXP*DH; i+=256){
    int e = i >> 8, k = i & 255;
    w2s[e][k] = W2[(size_t)k*NEXP + e];
  }
  __syncthreads();
  int lane = t & 63, w = t >> 6;
  int n = blockIdx.x*4 + w;
  if (n >= N) return;
  const float* r = rh + (size_t)n*DH;
  float p[NEXP];
  #pragma unroll
  for (int e=0;e<NEXP;e++) p[e] = 0.f;
  #pragma unroll
  for (int c=0;c<4;c++){
    int k = lane + c*64;
    float rv = r[k];
    #pragma unroll
    for (int e=0;e<NEXP;e++) p[e] += rv * w2s[e][k];
  }
  #pragma unroll
  for (int off=1; off<64; off<<=1){
    #pragma unroll
    for (int e=0;e<NEXP;e++) p[e] += __shfl_xor(p[e], off, 64);
  }
  if (lane == 0){
    float l0[NEXP];
    #pragma unroll
    for (int e=0;e<NEXP;e++) l0[e] = p[e] + b2[e];
    float m = l0[0];
    #pragma unroll
    for (int e=1;e<NEXP;e++) m = fmaxf(m, l0[e]);
    float ex[NEXP];
    #pragma unroll
    for (int e=0;e<NEXP;e++) ex[e] = expf(l0[e]-m);
    int e0=0; float b0v=ex[0];
    #pragma unroll
    for (int e=1;e<NEXP;e++) if (ex[e]>b0v){b0v=ex[e]; e0=e;}
    int e1=(e0==0)?1:0; float b1v=ex[e1];
    #pragma unroll
    for (int e=0;e<NEXP;e++) if (e!=e0 && ex[e]>b1v){b1v=ex[e]; e1=e;}
    float sv = b0v + b1v;
    rval[n*2]   = b0v/sv;
    rval[n*2+1] = b1v/sv;
    ridx[n*2]   = e0;
    ridx[n*2+1] = e1;
  }
}

// ---------------- routing scatter (hierarchical: LDS histogram + 8 global
// atomics per block instead of 2 per node) ----------------
__global__ __launch_bounds__(256) void rsort_k(const int* __restrict__ ridx,
    int* __restrict__ cnt, int* __restrict__ plist, int* __restrict__ ppos, int N){
  __shared__ int lcnt[NEXP];
  __shared__ int lbase[NEXP];
  int t = threadIdx.x;
  int n = blockIdx.x*256 + t;
  if (t < NEXP) lcnt[t] = 0;
  __syncthreads();
  int e0=0, e1=0, o0=0, o1=0;
  if (n < N){
    e0 = ridx[n*2];
    e1 = ridx[n*2+1];
    o0 = atomicAdd(&lcnt[e0], 1);
    o1 = atomicAdd(&lcnt[e1], 1);
  }
  __syncthreads();
  if (t < NEXP) lbase[t] = atomicAdd(&cnt[t], lcnt[t]);
  __syncthreads();
  if (n < N){
    int p0 = lbase[e0] + o0;
    int p1 = lbase[e1] + o1;
    plist[(size_t)e0*N + p0] = n;
    plist[(size_t)e1*N + p1] = n;
    ppos[n*2]   = p0;
    ppos[n*2+1] = p1;
  }
}

// ---------------- CSR aggregation (dense, batched over experts) ----------
template<int TAG>
__global__ __launch_bounds__(256) void aggregate_k(const u16* __restrict__ Hsrc,
    u16* __restrict__ Aout, const int* __restrict__ row_ptr,
    const int* __restrict__ csr_src, int N, long long srcStride){
  int e = blockIdx.y;
  const u16* H = Hsrc + (size_t)e*(size_t)srcStride;
  u16* A = Aout + (size_t)e*((size_t)N*DH);
  int node = blockIdx.x*4 + (threadIdx.x>>6);
  if (node >= N) return;
  int lane = threadIdx.x & 63;
  int beg = row_ptr[node], end = row_ptr[node+1];
  float a0=0.f,a1=0.f,a2=0.f,a3=0.f;
  const u16* Hl = H + (lane<<2);
  int i = beg;
  for (; i+8<=end; i+=8){
    int sarr[8];
    #pragma unroll
    for (int u=0;u<8;u++) sarr[u] = csr_src[i+u];
    #pragma unroll
    for (int u=0;u<8;u++){
      uint2 v = *(const uint2*)(Hl + ((size_t)sarr[u]<<8));
      a0 += bitsToF(v.x<<16);
      a1 += bitsToF(v.x & 0xffff0000u);
      a2 += bitsToF(v.y<<16);
      a3 += bitsToF(v.y & 0xffff0000u);
    }
  }
  for (; i<end; ++i){
    int s = csr_src[i];
    uint2 v = *(const uint2*)(Hl + ((size_t)s<<8));
    a0 += bitsToF(v.x<<16);
    a1 += bitsToF(v.x & 0xffff0000u);
    a2 += bitsToF(v.y<<16);
    a3 += bitsToF(v.y & 0xffff0000u);
  }
  uint2 o;
  o.x = ((u32)f2bf(a1)<<16) | f2bf(a0);
  o.y = ((u32)f2bf(a3)<<16) | f2bf(a2);
  *(uint2*)(A + ((size_t)node<<8) + (lane<<2)) = o;
}

// ---------------- sparse CSR aggregation + root-row compaction -------------
// writes Aout[e][idx] = sum_nbr H[e][*], Rout[e][idx] = H[e][node]
__global__ __launch_bounds__(256) void agg_sparse_k(const u16* __restrict__ Hsrc,
    u16* __restrict__ Aout, u16* __restrict__ Rout,
    const int* __restrict__ row_ptr, const int* __restrict__ csr_src,
    const int* __restrict__ plist, const int* __restrict__ cnt, int N){
  int e = blockIdx.y;
  int idx = blockIdx.x*4 + (threadIdx.x>>6);
  if (idx >= cnt[e]) return;
  int node = plist[(size_t)e*N + idx];
  size_t NS = (size_t)N*DH;
  const u16* H = Hsrc + (size_t)e*NS;
  int lane = threadIdx.x & 63;
  int beg = row_ptr[node], end = row_ptr[node+1];
  float a0=0.f,a1=0.f,a2=0.f,a3=0.f;
  const u16* Hl = H + (lane<<2);
  uint2 rootv = *(const uint2*)(Hl + ((size_t)node<<8));
  int i = beg;
  for (; i+8<=end; i+=8){
    int sarr[8];
    #pragma unroll
    for (int u=0;u<8;u++) sarr[u] = csr_src[i+u];
    #pragma unroll
    for (int u=0;u<8;u++){
      uint2 v = *(const uint2*)(Hl + ((size_t)sarr[u]<<8));
      a0 += bitsToF(v.x<<16);
      a1 += bitsToF(v.x & 0xffff0000u);
      a2 += bitsToF(v.y<<16);
      a3 += bitsToF(v.y & 0xffff0000u);
    }
  }
  for (; i<end; ++i){
    int s = csr_src[i];
    uint2 v = *(const uint2*)(Hl + ((size_t)s<<8));
    a0 += bitsToF(v.x<<16);
    a1 += bitsToF(v.x & 0xffff0000u);
    a2 += bitsToF(v.y<<16);
    a3 += bitsToF(v.y & 0xffff0000u);
  }
  uint2 o;
  o.x = ((u32)f2bf(a1)<<16) | f2bf(a0);
  o.y = ((u32)f2bf(a3)<<16) | f2bf(a2);
  *(uint2*)(Aout + (size_t)e*NS + ((size_t)idx<<8) + (lane<<2)) = o;
  *(uint2*)(Rout + (size_t)e*NS + ((size_t)idx<<8) + (lane<<2)) = rootv;
}

// ---------------- bf16 MFMA GEMM (m97 structure + source-swizzled LDS) -----
template<int TAG>
__global__ __launch_bounds__(256,2) void gemm_k(
    const u16* __restrict__ Aagg, long long strideA,
    const u16* __restrict__ Hroot, long long strideR,
    const u16* __restrict__ WT,
    const float* __restrict__ bias,
    u16* __restrict__ Hout,
    int N, int relu_flag)
{
  __shared__ u16 As[128*32];
  __shared__ u16 Bs[128*32];
  int e = blockIdx.z;
  const u16* aBase = Aagg + (size_t)e*(size_t)strideA;
  const u16* rBase = Hroot + (size_t)e*(size_t)strideR;
  const u16* wBase = WT + (size_t)e*(256*512);
  const float* be  = bias + e*256;
  u16* Oe = Hout + (size_t)e*((size_t)N*DH);

  int tid = threadIdx.x;
  int lane = tid & 63, w = tid >> 6;
  int wr = w >> 1, wc = w & 1;
  int m0 = blockIdx.x * 128;
  int n0 = blockIdx.y * 128;

  int lrow = lane >> 2;
  int q8   = (((lane & 3) ^ ((lane >> 3) & 3))) * 8;   // swizzled source piece
  int r0 = w*16 + lrow;
  int r1 = (w+4)*16 + lrow;
  int arow0 = m0 + r0; if (arow0 >= N) arow0 = N-1;
  int arow1 = m0 + r1; if (arow1 >= N) arow1 = N-1;
  long long aoff0 = (long long)arow0*256 + q8;
  long long aoff1 = (long long)arow1*256 + q8;
  long long boff0 = (long long)(n0 + r0)*512 + q8;
  long long boff1 = (long long)(n0 + r1)*512 + q8;
  u16* aL0 = As + (size_t)w*512;
  u16* aL1 = As + (size_t)(w+4)*512;
  u16* bL0 = Bs + (size_t)w*512;
  u16* bL1 = Bs + (size_t)(w+4)*512;

  f32x4 acc[4][4];
  #pragma unroll
  for (int a=0;a<4;a++)
    #pragma unroll
    for (int b=0;b<4;b++) acc[a][b] = (f32x4){0.f,0.f,0.f,0.f};

  int fr = lane & 15;
  int fk = (((lane >> 4) ^ ((fr >> 1) & 3))) * 8;      // swizzled read piece
  const u16* aRead = As + (size_t)(wr*64 + fr)*32 + fk;
  const u16* bRead = Bs + (size_t)(wc*64 + fr)*32 + fk;

  #pragma unroll 1
  for (int half=0; half<2; ++half){
    const u16* sA = half ? rBase : aBase;
    #pragma unroll 1
    for (int kk=0; kk<8; ++kk){
      int kin = kk*32;
      int kg  = half*256 + kin;
      GLOAD_LDS16(sA + aoff0 + kin, aL0);
      GLOAD_LDS16(sA + aoff1 + kin, aL1);
      GLOAD_LDS16(wBase + boff0 + kg, bL0);
      GLOAD_LDS16(wBase + boff1 + kg, bL1);
      __syncthreads();
      s16x8 af[4], bf[4];
      #pragma unroll
      for (int mi=0;mi<4;mi++) af[mi] = *(const s16x8*)(aRead + mi*16*32);
      #pragma unroll
      for (int ni=0;ni<4;ni++) bf[ni] = *(const s16x8*)(bRead + ni*16*32);
      #pragma unroll
      for (int mi=0;mi<4;mi++)
        #pragma unroll
        for (int ni=0;ni<4;ni++)
          acc[mi][ni] = __builtin_amdgcn_mfma_f32_16x16x32_bf16(af[mi], bf[ni], acc[mi][ni], 0, 0, 0);
      __syncthreads();
    }
  }
  int fq = lane >> 4;
  #pragma unroll
  for (int ni=0;ni<4;ni++){
    int col = n0 + wc*64 + ni*16 + fr;
    float bv = be[col];
    #pragma unroll
    for (int mi=0;mi<4;mi++){
      int rowb = m0 + wr*64 + mi*16 + fq*4;
      f32x4 v = acc[mi][ni];
      #pragma unroll
      for (int j=0;j<4;j++){
        int row = rowb + j;
        if (row < N){
          float o = v[j] + bv;
          if (relu_flag) o = fmaxf(o, 0.f);
          Oe[(size_t)row*DH + col] = f2bf(o);
        }
      }
    }
  }
}

// ---------------- sparse GEMM: fully compacted (linear A and root) ---------
__global__ __launch_bounds__(256,2) void gemm_sparse_k(
    const u16* __restrict__ Aagg,   // [e][cap N][256] compacted aggregates
    const u16* __restrict__ Rc,     // [e][cap N][256] compacted root rows
    const u16* __restrict__ WT,
    const float* __restrict__ bias,
    u16* __restrict__ Hout,         // [e][cap N][256] compacted
    const int* __restrict__ cnte,
    int N)
{
  __shared__ u16 As[128*32];
  __shared__ u16 Bs[128*32];
  int e = blockIdx.z;
  int cnt = cnte[e];
  int m0 = blockIdx.x * 128;
  if (m0 >= cnt) return;
  size_t NS = (size_t)N*DH;
  const u16* aBase = Aagg + (size_t)e*NS;
  const u16* rBase = Rc + (size_t)e*NS;
  const u16* wBase = WT + (size_t)e*(256*512);
  const float* be  = bias + e*256;
  u16* Oe = Hout + (size_t)e*NS;

  int tid = threadIdx.x;
  int lane = tid & 63, w = tid >> 6;
  int wr = w >> 1, wc = w & 1;
  int n0 = blockIdx.y * 128;

  int lrow = lane >> 2;
  int q8   = (((lane & 3) ^ ((lane >> 3) & 3))) * 8;
  int r0 = w*16 + lrow;
  int r1 = (w+4)*16 + lrow;
  int ai0 = m0 + r0; if (ai0 >= cnt) ai0 = cnt-1;
  int ai1 = m0 + r1; if (ai1 >= cnt) ai1 = cnt-1;
  long long aoff0 = (long long)ai0*256 + q8;
  long long aoff1 = (long long)ai1*256 + q8;
  long long boff0 = (long long)(n0 + r0)*512 + q8;
  long long boff1 = (long long)(n0 + r1)*512 + q8;
  u16* aL0 = As + (size_t)w*512;
  u16* aL1 = As + (size_t)(w+4)*512;
  u16* bL0 = Bs + (size_t)w*512;
  u16* bL1 = Bs + (size_t)(w+4)*512;

  f32x4 acc[4][4];
  #pragma unroll
  for (int a=0;a<4;a++)
    #pragma unroll
    for (int b=0;b<4;b++) acc[a][b] = (f32x4){0.f,0.f,0.f,0.f};

  int fr = lane & 15;
  int fk = (((lane >> 4) ^ ((fr >> 1) & 3))) * 8;
  const u16* aRead = As + (size_t)(wr*64 + fr)*32 + fk;
  const u16* bRead = Bs + (size_t)(wc*64 + fr)*32 + fk;

  #pragma unroll 1
  for (int half=0; half<2; ++half){
    const u16* sA = half ? rBase : aBase;
    #pragma unroll 1
    for (int kk=0; kk<8; ++kk){
      int kin = kk*32;
      int kg  = half*256 + kin;
      GLOAD_LDS16(sA + aoff0 + kin, aL0);
      GLOAD_LDS16(sA + aoff1 + kin, aL1);
      GLOAD_LDS16(wBase + boff0 + kg, bL0);
      GLOAD_LDS16(wBase + boff1 + kg, bL1);
      __syncthreads();
      s16x8 af[4], bf[4];
      #pragma unroll
      for (int mi=0;mi<4;mi++) af[mi] = *(const s16x8*)(aRead + mi*16*32);
      #pragma unroll
      for (int ni=0;ni<4;ni++) bf[ni] = *(const s16x8*)(bRead + ni*16*32);
      #pragma unroll
      for (int mi=0;mi<4;mi++)
        #pragma unroll
        for (int ni=0;ni<4;ni++)
          acc[mi][ni] = __builtin_amdgcn_mfma_f32_16x16x32_bf16(af[mi], bf[ni], acc[mi][ni], 0, 0, 0);
      __syncthreads();
    }
  }
  int fq = lane >> 4;
  #pragma unroll
  for (int ni=0;ni<4;ni++){
    int col = n0 + wc*64 + ni*16 + fr;
    float bv = be[col];
    #pragma unroll
    for (int mi=0;mi<4;mi++){
      int rowb = m0 + wr*64 + mi*16 + fq*4;
      f32x4 v = acc[mi][ni];
      #pragma unroll
      for (int j=0;j<4;j++){
        int row = rowb + j;
        if (row < cnt){
          float o = v[j] + bv;
          Oe[(size_t)row*DH + col] = f2bf(o);
        }
      }
    }
  }
}

// ---------------- combine (sparse, indirected) ----------------
__global__ __launch_bounds__(256) void combine_sparse_k(const u16* __restrict__ H3c,
    const int* __restrict__ ridx, const int* __restrict__ ppos,
    const float* __restrict__ rval, float* __restrict__ out, int N){
  int n = blockIdx.x; if (n>=N) return;
  int f = threadIdx.x;
  int e0 = ridx[n*2], e1 = ridx[n*2+1];
  int p0 = ppos[n*2], p1 = ppos[n*2+1];
  float v0 = rval[n*2], v1 = rval[n*2+1];
  float h0 = bitsToF(((u32)H3c[((size_t)e0*N + p0)*DH + f])<<16);
  float h1 = bitsToF(((u32)H3c[((size_t)e1*N + p1)*DH + f])<<16);
  out[(size_t)n*DH + f] = v0*h0 + v1*h1;
}

// grouped dense fallback combine
__global__ __launch_bounds__(256) void combine_acc_k(const u16* __restrict__ H3,
    const int* __restrict__ ridx, const float* __restrict__ rval,
    float* __restrict__ out, int N, int eBase, int ezCnt){
  int n = blockIdx.x; if (n>=N) return;
  int f = threadIdx.x;
  size_t es = (size_t)N*DH;
  size_t off = (size_t)n*DH + f;
  float acc = out[off];
  #pragma unroll
  for (int p=0;p<2;p++){
    int e = ridx[n*2+p] - eBase;
    if (e >= 0 && e < ezCnt)
      acc += rval[n*2+p] * bitsToF(((u32)H3[(size_t)e*es + off])<<16);
  }
  out[off] = acc;
}

extern "C" void kernel_launch(void* const* d_in, const int* in_sizes, int n_in,
                              void* d_out, int out_size, void* d_ws, size_t ws_size,
                              hipStream_t stream)
{
  const float* x    = (const float*)d_in[0];
  const int*   ei   = (const int*)d_in[1];
  const int*   batch= (const int*)d_in[2];
  const float* encW = (const float*)d_in[3];
  const float* encb = (const float*)d_in[4];
  const float* rW1  = (const float*)d_in[5];
  const float* rb1  = (const float*)d_in[6];
  const float* rW2  = (const float*)d_in[7];
  const float* rb2  = (const float*)d_in[8];
  const float* Wrel = (const float*)d_in[9];
  const float* brel = (const float*)d_in[10];
  const float* Wroot= (const float*)d_in[11];
  int N = in_sizes[2];
  int E = in_sizes[1]/2;
  float* out = (float*)d_out;
  (void)n_in; (void)out_size;

  size_t NS = (size_t)N*DH;
  char* p = (char*)d_ws;
  auto carve = [&](size_t bytes)->char*{
    char* r = p; p += (bytes + 255) & ~(size_t)255; return r;
  };
  u16*  bh   = (u16*)carve(NS*2);
  u16*  WT   = (u16*)carve((size_t)3*NEXP*256*512*2);
  int*  deg  = (int*)carve((size_t)N*4 + 64*4);
  int*  ng   = deg + N;
  int*  eg   = ng + GNUM;
  int*  row_ptr = (int*)carve(((size_t)N+1)*4);
  int*  cursor  = (int*)carve((size_t)N*4);
  int*  csr     = (int*)carve((size_t)E*4);
  float* sizef  = (float*)carve(GNUM*2*4);
  int*  ridx    = (int*)carve((size_t)N*2*4);
  float* rvalv  = (float*)carve((size_t)N*2*4);
  int*  ecnt    = (int*)carve(NEXP*4);
  int*  plist   = (int*)carve((size_t)NEXP*N*4);
  int*  ppos    = (int*)carve((size_t)N*2*4);
  u16*  A0      = (u16*)carve(NS*2);
  size_t baseUsed = (size_t)(p - (char*)d_ws);

  int EZ = 0;
  for (int cand = NEXP; cand >= 1; cand >>= 1){
    if (baseUsed + (size_t)cand*3*NS*2 <= ws_size){ EZ = cand; break; }
  }
  if (EZ == 0){ mark_fail_k<<<1,1,0,stream>>>(out); return; }

  u16* Abuf = (u16*)carve((size_t)EZ*NS*2);
  u16* Hn   = (u16*)carve((size_t)EZ*NS*2);
  u16* Hc   = (u16*)carve((size_t)EZ*NS*2);
  float* hf; float* rh;
  if (EZ >= 2){ hf = (float*)Abuf; rh = (float*)Hn; }
  else {
    hf = (float*)carve(NS*4);
    rh = (float*)carve(NS*4);
    if ((size_t)(p - (char*)d_ws) > ws_size){ mark_fail_k<<<1,1,0,stream>>>(out); return; }
  }

  hipMemsetAsync(deg, 0, (size_t)N*4 + (size_t)2*GNUM*4, stream);
  hipMemsetAsync(ecnt, 0, NEXP*4, stream);
  if (EZ != NEXP) hipMemsetAsync(out, 0, NS*4, stream);

  int eb = (E + 255)/256;
  count_edges_k<<<eb, 256, 0, stream>>>(ei, batch, deg, eg, E);
  count_nodes_k<<<(N+255)/256, 256, 0, stream>>>(batch, ng, N);
  scan_deg_k<<<1, SCAN_T, 0, stream>>>(deg, row_ptr, cursor, N);
  scatter_edges_k<<<eb, 256, 0, stream>>>(ei, cursor, csr, E);
  size_feats_k<<<1, 64, 0, stream>>>(ng, eg, sizef);
  encoder_k<<<N, 256, 0, stream>>>(x, encW, encb, hf, bh, N);
  convw_k<<<dim3(16,2,3*NEXP), dim3(64,4), 0, stream>>>(Wrel, Wroot, WT);
  router1_k<<<(N+R1N-1)/R1N, 256, 0, stream>>>(hf, sizef, batch, rW1, rb1, rh, N);
  router2_k<<<(N+3)/4, 256, 0, stream>>>(rh, rW2, rb2, ridx, rvalv, N);
  rsort_k<<<(N+255)/256, 256, 0, stream>>>(ridx, ecnt, plist, ppos, N);

  int aggx = (N+3)/4;
  int mt = (N+127)/128;
  const size_t WE = (size_t)256*512;

  aggregate_k<0><<<dim3(aggx,1), 256, 0, stream>>>(bh, A0, row_ptr, csr, N, 0);

  if (EZ == NEXP){
    // dense layers 0-1, routing-sparse layer 2
    gemm_k<0><<<dim3(mt,2,NEXP), 256, 0, stream>>>(A0, 0, bh, 0,
        WT, brel, Hc, N, 1);
    aggregate_k<1><<<dim3(aggx,NEXP), 256, 0, stream>>>(Hc, Abuf, row_ptr, csr, N, (long long)NS);
    gemm_k<1><<<dim3(mt,2,NEXP), 256, 0, stream>>>(Abuf, (long long)NS, Hc, (long long)NS,
        WT + (size_t)1*NEXP*WE, brel + 1*NEXP*256, Hn, N, 1);
    // Hc is dead now -> reuse as compacted-root buffer Rc.
    agg_sparse_k<<<dim3(aggx,NEXP), 256, 0, stream>>>(Hn, Abuf, Hc, row_ptr, csr, plist, ecnt, N);
    // gemm_sparse reads Abuf+Hc (compacted, linear), writes compacted H3 into Hn
    // (dense Hn fully consumed by agg_sparse; stream-ordered).
    gemm_sparse_k<<<dim3(mt,2,NEXP), 256, 0, stream>>>(Abuf, Hc,
        WT + (size_t)2*NEXP*WE, brel + 2*NEXP*256, Hn, ecnt, N);
    combine_sparse_k<<<N, 256, 0, stream>>>(Hn, ridx, ppos, rvalv, out, N);
  } else {
    for (int g = 0; g < NEXP; g += EZ){
      gemm_k<0><<<dim3(mt,2,EZ), 256, 0, stream>>>(A0, 0, bh, 0,
          WT + ((size_t)0*NEXP + g)*WE, brel + (0*NEXP + g)*256, Hc, N, 1);
      aggregate_k<1><<<dim3(aggx,EZ), 256, 0, stream>>>(Hc, Abuf, row_ptr, csr, N, (long long)NS);
      gemm_k<1><<<dim3(mt,2,EZ), 256, 0, stream>>>(Abuf, (long long)NS, Hc, (long long)NS,
          WT + ((size_t)1*NEXP + g)*WE, brel + (1*NEXP + g)*256, Hn, N, 1);
      aggregate_k<2><<<dim3(aggx,EZ), 256, 0, stream>>>(Hn, Abuf, row_ptr, csr, N, (long long)NS);
      gemm_k<2><<<dim3(mt,2,EZ), 256, 0, stream>>>(Abuf, (long long)NS, Hn, (long long)NS,
          WT + ((size_t)2*NEXP + g)*WE, brel + (2*NEXP + g)*256, Hc, N, 0);
      combine_acc_k<<<N, 256, 0, stream>>>(Hc, ridx, rvalv, out, N, g, EZ);
    }
  }
}

// Round 9
// 1697.685 us; speedup vs baseline: 1.2543x; 1.0002x over previous
//
#include <hip/hip_runtime.h>
#include <hip/hip_bf16.h>
#include <math.h>

#define NEXP 8
#define GNUM 16
#define DH 256

typedef __attribute__((ext_vector_type(8))) short s16x8;
typedef __attribute__((ext_vector_type(4))) float f32x4;
typedef unsigned short u16;
typedef unsigned int u32;

__device__ __forceinline__ float bitsToF(u32 b){ union{u32 u; float f;} c; c.u=b; return c.f; }
__device__ __forceinline__ u16 f2bf(float f){
  union{float f; u32 u;} c; c.f=f;
  u32 r = c.u + 0x7fffu + ((c.u>>16)&1u);
  return (u16)(r>>16);
}

#define GLOAD_LDS16(gp, lp) __builtin_amdgcn_global_load_lds( \
    (const __attribute__((address_space(1))) unsigned int*)(gp), \
    (__attribute__((address_space(3))) unsigned int*)(lp), 16, 0, 0)

// ---------------- CSR build ----------------
__global__ void count_edges_k(const int* __restrict__ ei, const int* __restrict__ batch,
                              int* __restrict__ deg, int* __restrict__ eg, int E){
  __shared__ int leg[GNUM];
  int t = threadIdx.x;
  if (t < GNUM) leg[t] = 0;
  __syncthreads();
  int i = blockIdx.x*blockDim.x + t;
  if (i < E){
    int s = ei[i];
    int d = ei[E + i];
    atomicAdd(&deg[d], 1);
    atomicAdd(&leg[batch[s]], 1);
  }
  __syncthreads();
  if (t < GNUM){ int v = leg[t]; if (v) atomicAdd(&eg[t], v); }
}

__global__ void count_nodes_k(const int* __restrict__ batch, int* __restrict__ ng, int N){
  __shared__ int lng[GNUM];
  int t = threadIdx.x;
  if (t < GNUM) lng[t] = 0;
  __syncthreads();
  int i = blockIdx.x*blockDim.x + t;
  if (i < N) atomicAdd(&lng[batch[i]], 1);
  __syncthreads();
  if (t < GNUM){ int v = lng[t]; if (v) atomicAdd(&ng[t], v); }
}

#define SCAN_T 1024
#define SCAN_CH 32
__global__ __launch_bounds__(1024) void scan_deg_k(const int* __restrict__ deg,
    int* __restrict__ row_ptr, int* __restrict__ cursor, int N){
  __shared__ int part[SCAN_T];
  int t = threadIdx.x;
  int base = t*SCAN_CH;
  int loc[SCAN_CH];
  int s = 0;
  #pragma unroll
  for (int j=0;j<SCAN_CH;j++){
    int i = base+j;
    int v = (i<N)? deg[i] : 0;
    loc[j] = s; s += v;
  }
  part[t] = s;
  __syncthreads();
  for (int off=1; off<SCAN_T; off<<=1){
    int add = (t>=off)? part[t-off] : 0;
    __syncthreads();
    part[t] += add;
    __syncthreads();
  }
  int ex = (t==0)? 0 : part[t-1];
  #pragma unroll
  for (int j=0;j<SCAN_CH;j++){
    int i = base+j;
    if (i<N){ int v = ex + loc[j]; row_ptr[i]=v; cursor[i]=v; }
  }
  if (t == SCAN_T-1) row_ptr[N] = part[SCAN_T-1];
}

__global__ void scatter_edges_k(const int* __restrict__ ei, int* __restrict__ cursor,
                                int* __restrict__ csr_src, int E){
  int i = blockIdx.x*blockDim.x + threadIdx.x;
  if (i>=E) return;
  int s = ei[i];
  int d = ei[E + i];
  int pos = atomicAdd(&cursor[d], 1);
  csr_src[pos] = s;
}

__global__ void size_feats_k(const int* __restrict__ ng, const int* __restrict__ eg,
                             float* __restrict__ sizef){
  int g = threadIdx.x;
  if (g < GNUM){
    sizef[g*2]   = logf(fmaxf((float)ng[g], 1.f));
    sizef[g*2+1] = logf(fmaxf((float)eg[g], 1.f));
  }
}

__global__ void mark_fail_k(float* out){ out[0] = __builtin_nanf(""); }

// ---------------- encoder ----------------
__global__ __launch_bounds__(256) void encoder_k(const float* __restrict__ x,
    const float* __restrict__ W, const float* __restrict__ b,
    float* __restrict__ hf, u16* __restrict__ bh, int N){
  int n = blockIdx.x; if (n>=N) return;
  int f = threadIdx.x;
  float acc = b[f];
  #pragma unroll
  for (int k=0;k<6;k++) acc += x[n*6+k]*W[k*DH+f];
  acc = fmaxf(acc, 0.f);
  hf[(size_t)n*DH+f] = acc;
  bh[(size_t)n*DH+f] = f2bf(acc);
}

// ---------------- weight convert ----------------
__global__ __launch_bounds__(256) void convw_k(const float* __restrict__ Wrel,
    const float* __restrict__ Wroot, u16* __restrict__ WT){
  __shared__ float tile[64][65];
  int tx = threadIdx.x;
  int ty = threadIdx.y;
  int kt = blockIdx.x & 3, ct = blockIdx.x >> 2;
  int srcRoot = blockIdx.y;
  int le = blockIdx.z;
  const float* src = (srcRoot ? Wroot : Wrel) + (size_t)le*65536;
  #pragma unroll
  for (int i=0;i<16;i++){
    int kl = ty + i*4;
    tile[kl][tx] = src[(size_t)(kt*64 + kl)*256 + ct*64 + tx];
  }
  __syncthreads();
  u16* dst = WT + (size_t)le*131072 + (srcRoot ? 256 : 0) + kt*64;
  #pragma unroll
  for (int i=0;i<16;i++){
    int cl = ty + i*4;
    dst[(size_t)(ct*64 + cl)*512 + tx] = f2bf(tile[tx][cl]);
  }
}

// ---------------- router layer 1 ----------------
#define R1N 32
__global__ __launch_bounds__(256) void router1_k(
    const float* __restrict__ hf, const float* __restrict__ sizef,
    const int* __restrict__ batch,
    const float* __restrict__ W1, const float* __restrict__ b1,
    float* __restrict__ rh, int N)
{
  __shared__ float xin[R1N][264];
  int t = threadIdx.x;
  int lane = t & 63, w = t >> 6;
  int n0 = blockIdx.x * R1N;
  #pragma unroll
  for (int i=0;i<R1N;i++){
    int n = n0 + i;
    xin[i][t] = (n<N) ? hf[(size_t)n*DH + t] : 0.f;
  }
  if (t < R1N){
    int n = n0 + t;
    int g = (n<N) ? (int)batch[n] : 0;
    xin[t][256] = sizef[g*2];
    xin[t][257] = sizef[g*2+1];
    xin[t][258] = 0.f; xin[t][259] = 0.f;
    xin[t][260] = 0.f; xin[t][261] = 0.f; xin[t][262] = 0.f; xin[t][263] = 0.f;
  }
  __syncthreads();

  int wn = w*8;
  float bb[4];
  #pragma unroll
  for (int c=0;c<4;c++) bb[c] = b1[lane + c*64];
  float acc[8][4];
  #pragma unroll
  for (int i=0;i<8;i++)
    #pragma unroll
    for (int c=0;c<4;c++) acc[i][c] = bb[c];

  #pragma unroll 2
  for (int k4=0; k4<256; k4+=4){
    float w4[4][4];
    #pragma unroll
    for (int j=0;j<4;j++)
      #pragma unroll
      for (int c=0;c<4;c++)
        w4[j][c] = W1[(size_t)(k4+j)*DH + lane + c*64];
    #pragma unroll
    for (int i=0;i<8;i++){
      f32x4 xv = *(const f32x4*)&xin[wn+i][k4];
      #pragma unroll
      for (int j=0;j<4;j++)
        #pragma unroll
        for (int c=0;c<4;c++)
          acc[i][c] += xv[j]*w4[j][c];
    }
  }
  float w256[4], w257[4];
  #pragma unroll
  for (int c=0;c<4;c++){
    w256[c] = W1[(size_t)256*DH + lane + c*64];
    w257[c] = W1[(size_t)257*DH + lane + c*64];
  }
  #pragma unroll
  for (int i=0;i<8;i++){
    float s0 = xin[wn+i][256], s1 = xin[wn+i][257];
    #pragma unroll
    for (int c=0;c<4;c++) acc[i][c] += s0*w256[c] + s1*w257[c];
  }
  #pragma unroll
  for (int i=0;i<8;i++){
    int n = n0 + wn + i;
    if (n < N){
      #pragma unroll
      for (int c=0;c<4;c++)
        rh[(size_t)n*DH + lane + c*64] = fmaxf(acc[i][c], 0.f);
    }
  }
}

// ---------------- router layer 2 + softmax + top2 ----------------
__global__ __launch_bounds__(256) void router2_k(
    const float* __restrict__ rh, const float* __restrict__ W2,
    const float* __restrict__ b2,
    int* __restrict__ ridx, float* __restrict__ rval, int N)
{
  __shared__ float w2s[NEXP][260];
  int t = threadIdx.x;
  for (int i=t; i<NEXP*DH; i+=256){
    int e = i >> 8, k = i & 255;
    w2s[e][k] = W2[(size_t)k*NEXP + e];
  }
  __syncthreads();
  int lane = t & 63, w = t >> 6;
  int n = blockIdx.x*4 + w;
  if (n >= N) return;
  const float* r = rh + (size_t)n*DH;
  float p[NEXP];
  #pragma unroll
  for (int e=0;e<NEXP;e++) p[e] = 0.f;
  #pragma unroll
  for (int c=0;c<4;c++){
    int k = lane + c*64;
    float rv = r[k];
    #pragma unroll
    for (int e=0;e<NEXP;e++) p[e] += rv * w2s[e][k];
  }
  #pragma unroll
  for (int off=1; off<64; off<<=1){
    #pragma unroll
    for (int e=0;e<NEXP;e++) p[e] += __shfl_xor(p[e], off, 64);
  }
  if (lane == 0){
    float l0[NEXP];
    #pragma unroll
    for (int e=0;e<NEXP;e++) l0[e] = p[e] + b2[e];
    float m = l0[0];
    #pragma unroll
    for (int e=1;e<NEXP;e++) m = fmaxf(m, l0[e]);
    float ex[NEXP];
    #pragma unroll
    for (int e=0;e<NEXP;e++) ex[e] = expf(l0[e]-m);
    int e0=0; float b0v=ex[0];
    #pragma unroll
    for (int e=1;e<NEXP;e++) if (ex[e]>b0v){b0v=ex[e]; e0=e;}
    int e1=(e0==0)?1:0; float b1v=ex[e1];
    #pragma unroll
    for (int e=0;e<NEXP;e++) if (e!=e0 && ex[e]>b1v){b1v=ex[e]; e1=e;}
    float sv = b0v + b1v;
    rval[n*2]   = b0v/sv;
    rval[n*2+1] = b1v/sv;
    ridx[n*2]   = e0;
    ridx[n*2+1] = e1;
  }
}

// ---------------- routing scatter (hierarchical) ----------------
__global__ __launch_bounds__(256) void rsort_k(const int* __restrict__ ridx,
    int* __restrict__ cnt, int* __restrict__ plist, int* __restrict__ ppos, int N){
  __shared__ int lcnt[NEXP];
  __shared__ int lbase[NEXP];
  int t = threadIdx.x;
  int n = blockIdx.x*256 + t;
  if (t < NEXP) lcnt[t] = 0;
  __syncthreads();
  int e0=0, e1=0, o0=0, o1=0;
  if (n < N){
    e0 = ridx[n*2];
    e1 = ridx[n*2+1];
    o0 = atomicAdd(&lcnt[e0], 1);
    o1 = atomicAdd(&lcnt[e1], 1);
  }
  __syncthreads();
  if (t < NEXP) lbase[t] = atomicAdd(&cnt[t], lcnt[t]);
  __syncthreads();
  if (n < N){
    int p0 = lbase[e0] + o0;
    int p1 = lbase[e1] + o1;
    plist[(size_t)e0*N + p0] = n;
    plist[(size_t)e1*N + p1] = n;
    ppos[n*2]   = p0;
    ppos[n*2+1] = p1;
  }
}

// ---------------- aggregation device body ----------------
__device__ __forceinline__ void agg_row(const u16* __restrict__ H,
    u16* __restrict__ Arow, const int* __restrict__ row_ptr,
    const int* __restrict__ csr_src, int node, int lane){
  int beg = row_ptr[node], end = row_ptr[node+1];
  float a0=0.f,a1=0.f,a2=0.f,a3=0.f;
  const u16* Hl = H + (lane<<2);
  int i = beg;
  for (; i+8<=end; i+=8){
    int sarr[8];
    #pragma unroll
    for (int u=0;u<8;u++) sarr[u] = csr_src[i+u];
    #pragma unroll
    for (int u=0;u<8;u++){
      uint2 v = *(const uint2*)(Hl + ((size_t)sarr[u]<<8));
      a0 += bitsToF(v.x<<16);
      a1 += bitsToF(v.x & 0xffff0000u);
      a2 += bitsToF(v.y<<16);
      a3 += bitsToF(v.y & 0xffff0000u);
    }
  }
  for (; i<end; ++i){
    int s = csr_src[i];
    uint2 v = *(const uint2*)(Hl + ((size_t)s<<8));
    a0 += bitsToF(v.x<<16);
    a1 += bitsToF(v.x & 0xffff0000u);
    a2 += bitsToF(v.y<<16);
    a3 += bitsToF(v.y & 0xffff0000u);
  }
  uint2 o;
  o.x = ((u32)f2bf(a1)<<16) | f2bf(a0);
  o.y = ((u32)f2bf(a3)<<16) | f2bf(a2);
  *(uint2*)(Arow + (lane<<2)) = o;
}

// layer-0 shared aggregate (single table)
__global__ __launch_bounds__(256) void agg0_k(const u16* __restrict__ H,
    u16* __restrict__ A, const int* __restrict__ row_ptr,
    const int* __restrict__ csr_src, int N){
  int node = blockIdx.x*4 + (threadIdx.x>>6);
  if (node >= N) return;
  int lane = threadIdx.x & 63;
  agg_row(H, A + ((size_t)node<<8), row_ptr, csr_src, node, lane);
}

// layer-1 dense aggregate, expert->XCD pinned, half node-range [base, base+cntN)
__device__ __forceinline__ void agg1_body(const u16* __restrict__ Hsrc,
    u16* __restrict__ Aout, const int* __restrict__ row_ptr,
    const int* __restrict__ csr_src, int N, int base, int cntN){
  int bid = blockIdx.x;
  int e  = bid & 7;            // expert -> XCD pin (round-robin dispatch)
  int xb = bid >> 3;
  int node = base + xb*4 + (threadIdx.x>>6);
  if (node >= base + cntN) return;
  int lane = threadIdx.x & 63;
  size_t NS = (size_t)N*DH;
  agg_row(Hsrc + (size_t)e*NS, Aout + (size_t)e*NS + ((size_t)node<<8),
          row_ptr, csr_src, node, lane);
}
__global__ __launch_bounds__(256) void agg1a_k(const u16* __restrict__ Hsrc,
    u16* __restrict__ Aout, const int* __restrict__ row_ptr,
    const int* __restrict__ csr_src, int N, int base, int cntN){
  agg1_body(Hsrc, Aout, row_ptr, csr_src, N, base, cntN);
}
__global__ __launch_bounds__(256) void agg1b_k(const u16* __restrict__ Hsrc,
    u16* __restrict__ Aout, const int* __restrict__ row_ptr,
    const int* __restrict__ csr_src, int N, int base, int cntN){
  agg1_body(Hsrc, Aout, row_ptr, csr_src, N, base, cntN);
}

// sparse aggregate + root compaction
__global__ __launch_bounds__(256) void agg2s_k(const u16* __restrict__ Hsrc,
    u16* __restrict__ Aout, u16* __restrict__ Rout,
    const int* __restrict__ row_ptr, const int* __restrict__ csr_src,
    const int* __restrict__ plist, const int* __restrict__ cnt, int N){
  int e = blockIdx.y;
  int idx = blockIdx.x*4 + (threadIdx.x>>6);
  if (idx >= cnt[e]) return;
  int node = plist[(size_t)e*N + idx];
  size_t NS = (size_t)N*DH;
  const u16* H = Hsrc + (size_t)e*NS;
  int lane = threadIdx.x & 63;
  uint2 rootv = *(const uint2*)(H + ((size_t)node<<8) + (lane<<2));
  agg_row(H, Aout + (size_t)e*NS + ((size_t)idx<<8), row_ptr, csr_src, node, lane);
  *(uint2*)(Rout + (size_t)e*NS + ((size_t)idx<<8) + (lane<<2)) = rootv;
}

// generic dense aggregate (fallback path only)
template<int TAG>
__global__ __launch_bounds__(256) void aggregate_k(const u16* __restrict__ Hsrc,
    u16* __restrict__ Aout, const int* __restrict__ row_ptr,
    const int* __restrict__ csr_src, int N, long long srcStride){
  int e = blockIdx.y;
  int node = blockIdx.x*4 + (threadIdx.x>>6);
  if (node >= N) return;
  int lane = threadIdx.x & 63;
  agg_row(Hsrc + (size_t)e*(size_t)srcStride,
          Aout + (size_t)e*((size_t)N*DH) + ((size_t)node<<8),
          row_ptr, csr_src, node, lane);
}

// ---------------- GEMM device body (m97 structure + swizzled LDS) ----------
__device__ __forceinline__ void gemm_dense_body(
    const u16* __restrict__ aBase, const u16* __restrict__ rBase,
    const u16* __restrict__ wBase, const float* __restrict__ be,
    u16* __restrict__ Oe, int N, int relu_flag, u16* As, u16* Bs)
{
  int tid = threadIdx.x;
  int lane = tid & 63, w = tid >> 6;
  int wr = w >> 1, wc = w & 1;
  int m0 = blockIdx.x * 128;
  int n0 = blockIdx.y * 128;

  int lrow = lane >> 2;
  int q8   = (((lane & 3) ^ ((lane >> 3) & 3))) * 8;
  int r0 = w*16 + lrow;
  int r1 = (w+4)*16 + lrow;
  int arow0 = m0 + r0; if (arow0 >= N) arow0 = N-1;
  int arow1 = m0 + r1; if (arow1 >= N) arow1 = N-1;
  long long aoff0 = (long long)arow0*256 + q8;
  long long aoff1 = (long long)arow1*256 + q8;
  long long boff0 = (long long)(n0 + r0)*512 + q8;
  long long boff1 = (long long)(n0 + r1)*512 + q8;
  u16* aL0 = As + (size_t)w*512;
  u16* aL1 = As + (size_t)(w+4)*512;
  u16* bL0 = Bs + (size_t)w*512;
  u16* bL1 = Bs + (size_t)(w+4)*512;

  f32x4 acc[4][4];
  #pragma unroll
  for (int a=0;a<4;a++)
    #pragma unroll
    for (int b=0;b<4;b++) acc[a][b] = (f32x4){0.f,0.f,0.f,0.f};

  int fr = lane & 15;
  int fk = (((lane >> 4) ^ ((fr >> 1) & 3))) * 8;
  const u16* aRead = As + (size_t)(wr*64 + fr)*32 + fk;
  const u16* bRead = Bs + (size_t)(wc*64 + fr)*32 + fk;

  #pragma unroll 1
  for (int half=0; half<2; ++half){
    const u16* sA = half ? rBase : aBase;
    #pragma unroll 1
    for (int kk=0; kk<8; ++kk){
      int kin = kk*32;
      int kg  = half*256 + kin;
      GLOAD_LDS16(sA + aoff0 + kin, aL0);
      GLOAD_LDS16(sA + aoff1 + kin, aL1);
      GLOAD_LDS16(wBase + boff0 + kg, bL0);
      GLOAD_LDS16(wBase + boff1 + kg, bL1);
      __syncthreads();
      s16x8 af[4], bf[4];
      #pragma unroll
      for (int mi=0;mi<4;mi++) af[mi] = *(const s16x8*)(aRead + mi*16*32);
      #pragma unroll
      for (int ni=0;ni<4;ni++) bf[ni] = *(const s16x8*)(bRead + ni*16*32);
      #pragma unroll
      for (int mi=0;mi<4;mi++)
        #pragma unroll
        for (int ni=0;ni<4;ni++)
          acc[mi][ni] = __builtin_amdgcn_mfma_f32_16x16x32_bf16(af[mi], bf[ni], acc[mi][ni], 0, 0, 0);
      __syncthreads();
    }
  }
  int fq = lane >> 4;
  #pragma unroll
  for (int ni=0;ni<4;ni++){
    int col = n0 + wc*64 + ni*16 + fr;
    float bv = be[col];
    #pragma unroll
    for (int mi=0;mi<4;mi++){
      int rowb = m0 + wr*64 + mi*16 + fq*4;
      f32x4 v = acc[mi][ni];
      #pragma unroll
      for (int j=0;j<4;j++){
        int row = rowb + j;
        if (row < N){
          float o = v[j] + bv;
          if (relu_flag) o = fmaxf(o, 0.f);
          Oe[(size_t)row*DH + col] = f2bf(o);
        }
      }
    }
  }
}

// layer-0: shared A0/bh, per-expert W
__global__ __launch_bounds__(256,2) void gemm0_k(
    const u16* __restrict__ A0, const u16* __restrict__ bh,
    const u16* __restrict__ WT, const float* __restrict__ bias,
    u16* __restrict__ Hout, int N){
  __shared__ u16 As[128*32];
  __shared__ u16 Bs[128*32];
  int e = blockIdx.z;
  gemm_dense_body(A0, bh, WT + (size_t)e*(256*512), bias + e*256,
                  Hout + (size_t)e*((size_t)N*DH), N, 1, As, Bs);
}
// layer-1: per-expert A/H/W
__global__ __launch_bounds__(256,2) void gemm1_k(
    const u16* __restrict__ Aagg, const u16* __restrict__ Hroot,
    const u16* __restrict__ WT, const float* __restrict__ bias,
    u16* __restrict__ Hout, int N){
  __shared__ u16 As[128*32];
  __shared__ u16 Bs[128*32];
  int e = blockIdx.z;
  size_t NS = (size_t)N*DH;
  gemm_dense_body(Aagg + (size_t)e*NS, Hroot + (size_t)e*NS,
                  WT + (size_t)e*(256*512), bias + e*256,
                  Hout + (size_t)e*NS, N, 1, As, Bs);
}
// generic (fallback path) with strides + relu flag
template<int TAG>
__global__ __launch_bounds__(256,2) void gemm_k(
    const u16* __restrict__ Aagg, long long strideA,
    const u16* __restrict__ Hroot, long long strideR,
    const u16* __restrict__ WT, const float* __restrict__ bias,
    u16* __restrict__ Hout, int N, int relu_flag){
  __shared__ u16 As[128*32];
  __shared__ u16 Bs[128*32];
  int e = blockIdx.z;
  gemm_dense_body(Aagg + (size_t)e*(size_t)strideA, Hroot + (size_t)e*(size_t)strideR,
                  WT + (size_t)e*(256*512), bias + e*256,
                  Hout + (size_t)e*((size_t)N*DH), N, relu_flag, As, Bs);
}

// sparse layer-2 GEMM: compacted linear A and root
__global__ __launch_bounds__(256,2) void gemm2s_k(
    const u16* __restrict__ Aagg, const u16* __restrict__ Rc,
    const u16* __restrict__ WT, const float* __restrict__ bias,
    u16* __restrict__ Hout, const int* __restrict__ cnte, int N)
{
  __shared__ u16 As[128*32];
  __shared__ u16 Bs[128*32];
  int e = blockIdx.z;
  int cnt = cnte[e];
  int m0 = blockIdx.x * 128;
  if (m0 >= cnt) return;
  size_t NS = (size_t)N*DH;
  const u16* aBase = Aagg + (size_t)e*NS;
  const u16* rBase = Rc + (size_t)e*NS;
  const u16* wBase = WT + (size_t)e*(256*512);
  const float* be  = bias + e*256;
  u16* Oe = Hout + (size_t)e*NS;

  int tid = threadIdx.x;
  int lane = tid & 63, w = tid >> 6;
  int wr = w >> 1, wc = w & 1;
  int n0 = blockIdx.y * 128;

  int lrow = lane >> 2;
  int q8   = (((lane & 3) ^ ((lane >> 3) & 3))) * 8;
  int r0 = w*16 + lrow;
  int r1 = (w+4)*16 + lrow;
  int ai0 = m0 + r0; if (ai0 >= cnt) ai0 = cnt-1;
  int ai1 = m0 + r1; if (ai1 >= cnt) ai1 = cnt-1;
  long long aoff0 = (long long)ai0*256 + q8;
  long long aoff1 = (long long)ai1*256 + q8;
  long long boff0 = (long long)(n0 + r0)*512 + q8;
  long long boff1 = (long long)(n0 + r1)*512 + q8;
  u16* aL0 = As + (size_t)w*512;
  u16* aL1 = As + (size_t)(w+4)*512;
  u16* bL0 = Bs + (size_t)w*512;
  u16* bL1 = Bs + (size_t)(w+4)*512;

  f32x4 acc[4][4];
  #pragma unroll
  for (int a=0;a<4;a++)
    #pragma unroll
    for (int b=0;b<4;b++) acc[a][b] = (f32x4){0.f,0.f,0.f,0.f};

  int fr = lane & 15;
  int fk = (((lane >> 4) ^ ((fr >> 1) & 3))) * 8;
  const u16* aRead = As + (size_t)(wr*64 + fr)*32 + fk;
  const u16* bRead = Bs + (size_t)(wc*64 + fr)*32 + fk;

  #pragma unroll 1
  for (int half=0; half<2; ++half){
    const u16* sA = half ? rBase : aBase;
    #pragma unroll 1
    for (int kk=0; kk<8; ++kk){
      int kin = kk*32;
      int kg  = half*256 + kin;
      GLOAD_LDS16(sA + aoff0 + kin, aL0);
      GLOAD_LDS16(sA + aoff1 + kin, aL1);
      GLOAD_LDS16(wBase + boff0 + kg, bL0);
      GLOAD_LDS16(wBase + boff1 + kg, bL1);
      __syncthreads();
      s16x8 af[4], bf[4];
      #pragma unroll
      for (int mi=0;mi<4;mi++) af[mi] = *(const s16x8*)(aRead + mi*16*32);
      #pragma unroll
      for (int ni=0;ni<4;ni++) bf[ni] = *(const s16x8*)(bRead + ni*16*32);
      #pragma unroll
      for (int mi=0;mi<4;mi++)
        #pragma unroll
        for (int ni=0;ni<4;ni++)
          acc[mi][ni] = __builtin_amdgcn_mfma_f32_16x16x32_bf16(af[mi], bf[ni], acc[mi][ni], 0, 0, 0);
      __syncthreads();
    }
  }
  int fq = lane >> 4;
  #pragma unroll
  for (int ni=0;ni<4;ni++){
    int col = n0 + wc*64 + ni*16 + fr;
    float bv = be[col];
    #pragma unroll
    for (int mi=0;mi<4;mi++){
      int rowb = m0 + wr*64 + mi*16 + fq*4;
      f32x4 v = acc[mi][ni];
      #pragma unroll
      for (int j=0;j<4;j++){
        int row = rowb + j;
        if (row < cnt){
          float o = v[j] + bv;
          Oe[(size_t)row*DH + col] = f2bf(o);
        }
      }
    }
  }
}

// ---------------- combine ----------------
__global__ __launch_bounds__(256) void combine_sparse_k(const u16* __restrict__ H3c,
    const int* __restrict__ ridx, const int* __restrict__ ppos,
    const float* __restrict__ rval, float* __restrict__ out, int N){
  int n = blockIdx.x; if (n>=N) return;
  int f = threadIdx.x;
  int e0 = ridx[n*2], e1 = ridx[n*2+1];
  int p0 = ppos[n*2], p1 = ppos[n*2+1];
  float v0 = rval[n*2], v1 = rval[n*2+1];
  float h0 = bitsToF(((u32)H3c[((size_t)e0*N + p0)*DH + f])<<16);
  float h1 = bitsToF(((u32)H3c[((size_t)e1*N + p1)*DH + f])<<16);
  out[(size_t)n*DH + f] = v0*h0 + v1*h1;
}

__global__ __launch_bounds__(256) void combine_acc_k(const u16* __restrict__ H3,
    const int* __restrict__ ridx, const float* __restrict__ rval,
    float* __restrict__ out, int N, int eBase, int ezCnt){
  int n = blockIdx.x; if (n>=N) return;
  int f = threadIdx.x;
  size_t es = (size_t)N*DH;
  size_t off = (size_t)n*DH + f;
  float acc = out[off];
  #pragma unroll
  for (int p=0;p<2;p++){
    int e = ridx[n*2+p] - eBase;
    if (e >= 0 && e < ezCnt)
      acc += rval[n*2+p] * bitsToF(((u32)H3[(size_t)e*es + off])<<16);
  }
  out[off] = acc;
}

extern "C" void kernel_launch(void* const* d_in, const int* in_sizes, int n_in,
                              void* d_out, int out_size, void* d_ws, size_t ws_size,
                              hipStream_t stream)
{
  const float* x    = (const float*)d_in[0];
  const int*   ei   = (const int*)d_in[1];
  const int*   batch= (const int*)d_in[2];
  const float* encW = (const float*)d_in[3];
  const float* encb = (const float*)d_in[4];
  const float* rW1  = (const float*)d_in[5];
  const float* rb1  = (const float*)d_in[6];
  const float* rW2  = (const float*)d_in[7];
  const float* rb2  = (const float*)d_in[8];
  const float* Wrel = (const float*)d_in[9];
  const float* brel = (const float*)d_in[10];
  const float* Wroot= (const float*)d_in[11];
  int N = in_sizes[2];
  int E = in_sizes[1]/2;
  float* out = (float*)d_out;
  (void)n_in; (void)out_size;

  size_t NS = (size_t)N*DH;
  char* p = (char*)d_ws;
  auto carve = [&](size_t bytes)->char*{
    char* r = p; p += (bytes + 255) & ~(size_t)255; return r;
  };
  u16*  bh   = (u16*)carve(NS*2);
  u16*  WT   = (u16*)carve((size_t)3*NEXP*256*512*2);
  int*  deg  = (int*)carve((size_t)N*4 + 64*4);
  int*  ng   = deg + N;
  int*  eg   = ng + GNUM;
  int*  row_ptr = (int*)carve(((size_t)N+1)*4);
  int*  cursor  = (int*)carve((size_t)N*4);
  int*  csr     = (int*)carve((size_t)E*4);
  float* sizef  = (float*)carve(GNUM*2*4);
  int*  ridx    = (int*)carve((size_t)N*2*4);
  float* rvalv  = (float*)carve((size_t)N*2*4);
  int*  ecnt    = (int*)carve(NEXP*4);
  int*  plist   = (int*)carve((size_t)NEXP*N*4);
  int*  ppos    = (int*)carve((size_t)N*2*4);
  u16*  A0      = (u16*)carve(NS*2);
  size_t baseUsed = (size_t)(p - (char*)d_ws);

  int EZ = 0;
  for (int cand = NEXP; cand >= 1; cand >>= 1){
    if (baseUsed + (size_t)cand*3*NS*2 <= ws_size){ EZ = cand; break; }
  }
  if (EZ == 0){ mark_fail_k<<<1,1,0,stream>>>(out); return; }

  u16* Abuf = (u16*)carve((size_t)EZ*NS*2);
  u16* Hn   = (u16*)carve((size_t)EZ*NS*2);
  u16* Hc   = (u16*)carve((size_t)EZ*NS*2);
  float* hf; float* rh;
  if (EZ >= 2){ hf = (float*)Abuf; rh = (float*)Hn; }
  else {
    hf = (float*)carve(NS*4);
    rh = (float*)carve(NS*4);
    if ((size_t)(p - (char*)d_ws) > ws_size){ mark_fail_k<<<1,1,0,stream>>>(out); return; }
  }

  hipMemsetAsync(deg, 0, (size_t)N*4 + (size_t)2*GNUM*4, stream);
  hipMemsetAsync(ecnt, 0, NEXP*4, stream);
  if (EZ != NEXP) hipMemsetAsync(out, 0, NS*4, stream);

  int eb = (E + 255)/256;
  count_edges_k<<<eb, 256, 0, stream>>>(ei, batch, deg, eg, E);
  count_nodes_k<<<(N+255)/256, 256, 0, stream>>>(batch, ng, N);
  scan_deg_k<<<1, SCAN_T, 0, stream>>>(deg, row_ptr, cursor, N);
  scatter_edges_k<<<eb, 256, 0, stream>>>(ei, cursor, csr, E);
  size_feats_k<<<1, 64, 0, stream>>>(ng, eg, sizef);
  encoder_k<<<N, 256, 0, stream>>>(x, encW, encb, hf, bh, N);
  convw_k<<<dim3(16,2,3*NEXP), dim3(64,4), 0, stream>>>(Wrel, Wroot, WT);
  router1_k<<<(N+R1N-1)/R1N, 256, 0, stream>>>(hf, sizef, batch, rW1, rb1, rh, N);
  router2_k<<<(N+3)/4, 256, 0, stream>>>(rh, rW2, rb2, ridx, rvalv, N);
  rsort_k<<<(N+255)/256, 256, 0, stream>>>(ridx, ecnt, plist, ppos, N);

  int aggx = (N+3)/4;
  int mt = (N+127)/128;
  const size_t WE = (size_t)256*512;

  agg0_k<<<aggx, 256, 0, stream>>>(bh, A0, row_ptr, csr, N);

  if (EZ == NEXP){
    gemm0_k<<<dim3(mt,2,NEXP), 256, 0, stream>>>(A0, bh, WT, brel, Hc, N);
    // dense layer-1 aggregate, split into two half-range dispatches,
    // expert->XCD pinned (1D grid, e = bid & 7)
    int half0 = (N+1)/2, half1 = N - half0;
    int g1a = ((half0+3)/4)*8, g1b = ((half1+3)/4)*8;
    agg1a_k<<<g1a, 256, 0, stream>>>(Hc, Abuf, row_ptr, csr, N, 0, half0);
    agg1b_k<<<g1b, 256, 0, stream>>>(Hc, Abuf, row_ptr, csr, N, half0, half1);
    gemm1_k<<<dim3(mt,2,NEXP), 256, 0, stream>>>(Abuf, Hc,
        WT + (size_t)1*NEXP*WE, brel + 1*NEXP*256, Hn, N);
    // Hc dead -> compacted-root buffer
    agg2s_k<<<dim3(aggx,NEXP), 256, 0, stream>>>(Hn, Abuf, Hc, row_ptr, csr, plist, ecnt, N);
    gemm2s_k<<<dim3(mt,2,NEXP), 256, 0, stream>>>(Abuf, Hc,
        WT + (size_t)2*NEXP*WE, brel + 2*NEXP*256, Hn, ecnt, N);
    combine_sparse_k<<<N, 256, 0, stream>>>(Hn, ridx, ppos, rvalv, out, N);
  } else {
    for (int g = 0; g < NEXP; g += EZ){
      gemm_k<0><<<dim3(mt,2,EZ), 256, 0, stream>>>(A0, 0, bh, 0,
          WT + ((size_t)0*NEXP + g)*WE, brel + (0*NEXP + g)*256, Hc, N, 1);
      aggregate_k<1><<<dim3(aggx,EZ), 256, 0, stream>>>(Hc, Abuf, row_ptr, csr, N, (long long)NS);
      gemm_k<1><<<dim3(mt,2,EZ), 256, 0, stream>>>(Abuf, (long long)NS, Hc, (long long)NS,
          WT + ((size_t)1*NEXP + g)*WE, brel + (1*NEXP + g)*256, Hn, N, 1);
      aggregate_k<2><<<dim3(aggx,EZ), 256, 0, stream>>>(Hn, Abuf, row_ptr, csr, N, (long long)NS);
      gemm_k<2><<<dim3(mt,2,EZ), 256, 0, stream>>>(Abuf, (long long)NS, Hn, (long long)NS,
          WT + ((size_t)2*NEXP + g)*WE, brel + (2*NEXP + g)*256, Hc, N, 0);
      combine_acc_k<<<N, 256, 0, stream>>>(Hc, ridx, rvalv, out, N, g, EZ);
    }
  }
}

// Round 10
// 1302.671 us; speedup vs baseline: 1.6347x; 1.3032x over previous
//
#include <hip/hip_runtime.h>
#include <hip/hip_bf16.h>
#include <math.h>

#define NEXP 8
#define GNUM 16
#define DH 256

typedef __attribute__((ext_vector_type(8))) short s16x8;
typedef __attribute__((ext_vector_type(4))) float f32x4;
typedef unsigned short u16;
typedef unsigned int u32;

__device__ __forceinline__ float bitsToF(u32 b){ union{u32 u; float f;} c; c.u=b; return c.f; }
__device__ __forceinline__ u16 f2bf(float f){
  union{float f; u32 u;} c; c.f=f;
  u32 r = c.u + 0x7fffu + ((c.u>>16)&1u);
  return (u16)(r>>16);
}

#define GLOAD_LDS16(gp, lp) __builtin_amdgcn_global_load_lds( \
    (const __attribute__((address_space(1))) unsigned int*)(gp), \
    (__attribute__((address_space(3))) unsigned int*)(lp), 16, 0, 0)

// ---------------- CSR build ----------------
__global__ void count_edges_k(const int* __restrict__ ei, const int* __restrict__ batch,
                              int* __restrict__ deg, int* __restrict__ eg, int E){
  __shared__ int leg[GNUM];
  int t = threadIdx.x;
  if (t < GNUM) leg[t] = 0;
  __syncthreads();
  int i = blockIdx.x*blockDim.x + t;
  if (i < E){
    int s = ei[i];
    int d = ei[E + i];
    atomicAdd(&deg[d], 1);
    atomicAdd(&leg[batch[s]], 1);
  }
  __syncthreads();
  if (t < GNUM){ int v = leg[t]; if (v) atomicAdd(&eg[t], v); }
}

__global__ void count_nodes_k(const int* __restrict__ batch, int* __restrict__ ng, int N){
  __shared__ int lng[GNUM];
  int t = threadIdx.x;
  if (t < GNUM) lng[t] = 0;
  __syncthreads();
  int i = blockIdx.x*blockDim.x + t;
  if (i < N) atomicAdd(&lng[batch[i]], 1);
  __syncthreads();
  if (t < GNUM){ int v = lng[t]; if (v) atomicAdd(&ng[t], v); }
}

#define SCAN_T 1024
#define SCAN_CH 32
__global__ __launch_bounds__(1024) void scan_deg_k(const int* __restrict__ deg,
    int* __restrict__ row_ptr, int* __restrict__ cursor, int N){
  __shared__ int part[SCAN_T];
  int t = threadIdx.x;
  int base = t*SCAN_CH;
  int loc[SCAN_CH];
  int s = 0;
  #pragma unroll
  for (int j=0;j<SCAN_CH;j++){
    int i = base+j;
    int v = (i<N)? deg[i] : 0;
    loc[j] = s; s += v;
  }
  part[t] = s;
  __syncthreads();
  for (int off=1; off<SCAN_T; off<<=1){
    int add = (t>=off)? part[t-off] : 0;
    __syncthreads();
    part[t] += add;
    __syncthreads();
  }
  int ex = (t==0)? 0 : part[t-1];
  #pragma unroll
  for (int j=0;j<SCAN_CH;j++){
    int i = base+j;
    if (i<N){ int v = ex + loc[j]; row_ptr[i]=v; cursor[i]=v; }
  }
  if (t == SCAN_T-1) row_ptr[N] = part[SCAN_T-1];
}

__global__ void scatter_edges_k(const int* __restrict__ ei, int* __restrict__ cursor,
                                int* __restrict__ csr_src, int E){
  int i = blockIdx.x*blockDim.x + threadIdx.x;
  if (i>=E) return;
  int s = ei[i];
  int d = ei[E + i];
  int pos = atomicAdd(&cursor[d], 1);
  csr_src[pos] = s;
}

__global__ void size_feats_k(const int* __restrict__ ng, const int* __restrict__ eg,
                             float* __restrict__ sizef){
  int g = threadIdx.x;
  if (g < GNUM){
    sizef[g*2]   = logf(fmaxf((float)ng[g], 1.f));
    sizef[g*2+1] = logf(fmaxf((float)eg[g], 1.f));
  }
}

__global__ void mark_fail_k(float* out){ out[0] = __builtin_nanf(""); }

// ---------------- encoder ----------------
__global__ __launch_bounds__(256) void encoder_k(const float* __restrict__ x,
    const float* __restrict__ W, const float* __restrict__ b,
    float* __restrict__ hf, u16* __restrict__ bh, int N){
  int n = blockIdx.x; if (n>=N) return;
  int f = threadIdx.x;
  float acc = b[f];
  #pragma unroll
  for (int k=0;k<6;k++) acc += x[n*6+k]*W[k*DH+f];
  acc = fmaxf(acc, 0.f);
  hf[(size_t)n*DH+f] = acc;
  bh[(size_t)n*DH+f] = f2bf(acc);
}

// ---------------- weight convert ----------------
__global__ __launch_bounds__(256) void convw_k(const float* __restrict__ Wrel,
    const float* __restrict__ Wroot, u16* __restrict__ WT){
  __shared__ float tile[64][65];
  int tx = threadIdx.x;
  int ty = threadIdx.y;
  int kt = blockIdx.x & 3, ct = blockIdx.x >> 2;
  int srcRoot = blockIdx.y;
  int le = blockIdx.z;
  const float* src = (srcRoot ? Wroot : Wrel) + (size_t)le*65536;
  #pragma unroll
  for (int i=0;i<16;i++){
    int kl = ty + i*4;
    tile[kl][tx] = src[(size_t)(kt*64 + kl)*256 + ct*64 + tx];
  }
  __syncthreads();
  u16* dst = WT + (size_t)le*131072 + (srcRoot ? 256 : 0) + kt*64;
  #pragma unroll
  for (int i=0;i<16;i++){
    int cl = ty + i*4;
    dst[(size_t)(ct*64 + cl)*512 + tx] = f2bf(tile[tx][cl]);
  }
}

// ---------------- router layer 1 ----------------
#define R1N 32
__global__ __launch_bounds__(256) void router1_k(
    const float* __restrict__ hf, const float* __restrict__ sizef,
    const int* __restrict__ batch,
    const float* __restrict__ W1, const float* __restrict__ b1,
    float* __restrict__ rh, int N)
{
  __shared__ float xin[R1N][264];
  int t = threadIdx.x;
  int lane = t & 63, w = t >> 6;
  int n0 = blockIdx.x * R1N;
  #pragma unroll
  for (int i=0;i<R1N;i++){
    int n = n0 + i;
    xin[i][t] = (n<N) ? hf[(size_t)n*DH + t] : 0.f;
  }
  if (t < R1N){
    int n = n0 + t;
    int g = (n<N) ? (int)batch[n] : 0;
    xin[t][256] = sizef[g*2];
    xin[t][257] = sizef[g*2+1];
    xin[t][258] = 0.f; xin[t][259] = 0.f;
    xin[t][260] = 0.f; xin[t][261] = 0.f; xin[t][262] = 0.f; xin[t][263] = 0.f;
  }
  __syncthreads();

  int wn = w*8;
  float bb[4];
  #pragma unroll
  for (int c=0;c<4;c++) bb[c] = b1[lane + c*64];
  float acc[8][4];
  #pragma unroll
  for (int i=0;i<8;i++)
    #pragma unroll
    for (int c=0;c<4;c++) acc[i][c] = bb[c];

  #pragma unroll 2
  for (int k4=0; k4<256; k4+=4){
    float w4[4][4];
    #pragma unroll
    for (int j=0;j<4;j++)
      #pragma unroll
      for (int c=0;c<4;c++)
        w4[j][c] = W1[(size_t)(k4+j)*DH + lane + c*64];
    #pragma unroll
    for (int i=0;i<8;i++){
      f32x4 xv = *(const f32x4*)&xin[wn+i][k4];
      #pragma unroll
      for (int j=0;j<4;j++)
        #pragma unroll
        for (int c=0;c<4;c++)
          acc[i][c] += xv[j]*w4[j][c];
    }
  }
  float w256[4], w257[4];
  #pragma unroll
  for (int c=0;c<4;c++){
    w256[c] = W1[(size_t)256*DH + lane + c*64];
    w257[c] = W1[(size_t)257*DH + lane + c*64];
  }
  #pragma unroll
  for (int i=0;i<8;i++){
    float s0 = xin[wn+i][256], s1 = xin[wn+i][257];
    #pragma unroll
    for (int c=0;c<4;c++) acc[i][c] += s0*w256[c] + s1*w257[c];
  }
  #pragma unroll
  for (int i=0;i<8;i++){
    int n = n0 + wn + i;
    if (n < N){
      #pragma unroll
      for (int c=0;c<4;c++)
        rh[(size_t)n*DH + lane + c*64] = fmaxf(acc[i][c], 0.f);
    }
  }
}

// ---------------- router layer 2 + softmax + top2 ----------------
__global__ __launch_bounds__(256) void router2_k(
    const float* __restrict__ rh, const float* __restrict__ W2,
    const float* __restrict__ b2,
    int* __restrict__ ridx, float* __restrict__ rval, int N)
{
  __shared__ float w2s[NEXP][260];
  int t = threadIdx.x;
  for (int i=t; i<NEXP*DH; i+=256){
    int e = i >> 8, k = i & 255;
    w2s[e][k] = W2[(size_t)k*NEXP + e];
  }
  __syncthreads();
  int lane = t & 63, w = t >> 6;
  int n = blockIdx.x*4 + w;
  if (n >= N) return;
  const float* r = rh + (size_t)n*DH;
  float p[NEXP];
  #pragma unroll
  for (int e=0;e<NEXP;e++) p[e] = 0.f;
  #pragma unroll
  for (int c=0;c<4;c++){
    int k = lane + c*64;
    float rv = r[k];
    #pragma unroll
    for (int e=0;e<NEXP;e++) p[e] += rv * w2s[e][k];
  }
  #pragma unroll
  for (int off=1; off<64; off<<=1){
    #pragma unroll
    for (int e=0;e<NEXP;e++) p[e] += __shfl_xor(p[e], off, 64);
  }
  if (lane == 0){
    float l0[NEXP];
    #pragma unroll
    for (int e=0;e<NEXP;e++) l0[e] = p[e] + b2[e];
    float m = l0[0];
    #pragma unroll
    for (int e=1;e<NEXP;e++) m = fmaxf(m, l0[e]);
    float ex[NEXP];
    #pragma unroll
    for (int e=0;e<NEXP;e++) ex[e] = expf(l0[e]-m);
    int e0=0; float b0v=ex[0];
    #pragma unroll
    for (int e=1;e<NEXP;e++) if (ex[e]>b0v){b0v=ex[e]; e0=e;}
    int e1=(e0==0)?1:0; float b1v=ex[e1];
    #pragma unroll
    for (int e=0;e<NEXP;e++) if (e!=e0 && ex[e]>b1v){b1v=ex[e]; e1=e;}
    float sv = b0v + b1v;
    rval[n*2]   = b0v/sv;
    rval[n*2+1] = b1v/sv;
    ridx[n*2]   = e0;
    ridx[n*2+1] = e1;
  }
}

// ---------------- routing scatter (hierarchical) ----------------
__global__ __launch_bounds__(256) void rsort_k(const int* __restrict__ ridx,
    int* __restrict__ cnt, int* __restrict__ plist, int* __restrict__ ppos, int N){
  __shared__ int lcnt[NEXP];
  __shared__ int lbase[NEXP];
  int t = threadIdx.x;
  int n = blockIdx.x*256 + t;
  if (t < NEXP) lcnt[t] = 0;
  __syncthreads();
  int e0=0, e1=0, o0=0, o1=0;
  if (n < N){
    e0 = ridx[n*2];
    e1 = ridx[n*2+1];
    o0 = atomicAdd(&lcnt[e0], 1);
    o1 = atomicAdd(&lcnt[e1], 1);
  }
  __syncthreads();
  if (t < NEXP) lbase[t] = atomicAdd(&cnt[t], lcnt[t]);
  __syncthreads();
  if (n < N){
    int p0 = lbase[e0] + o0;
    int p1 = lbase[e1] + o1;
    plist[(size_t)e0*N + p0] = n;
    plist[(size_t)e1*N + p1] = n;
    ppos[n*2]   = p0;
    ppos[n*2+1] = p1;
  }
}

// ---------------- aggregation device body ----------------
__device__ __forceinline__ void agg_row(const u16* __restrict__ H,
    u16* __restrict__ Arow, const int* __restrict__ row_ptr,
    const int* __restrict__ csr_src, int node, int lane){
  int beg = row_ptr[node], end = row_ptr[node+1];
  float a0=0.f,a1=0.f,a2=0.f,a3=0.f;
  const u16* Hl = H + (lane<<2);
  int i = beg;
  for (; i+8<=end; i+=8){
    int sarr[8];
    #pragma unroll
    for (int u=0;u<8;u++) sarr[u] = csr_src[i+u];
    #pragma unroll
    for (int u=0;u<8;u++){
      uint2 v = *(const uint2*)(Hl + ((size_t)sarr[u]<<8));
      a0 += bitsToF(v.x<<16);
      a1 += bitsToF(v.x & 0xffff0000u);
      a2 += bitsToF(v.y<<16);
      a3 += bitsToF(v.y & 0xffff0000u);
    }
  }
  for (; i<end; ++i){
    int s = csr_src[i];
    uint2 v = *(const uint2*)(Hl + ((size_t)s<<8));
    a0 += bitsToF(v.x<<16);
    a1 += bitsToF(v.x & 0xffff0000u);
    a2 += bitsToF(v.y<<16);
    a3 += bitsToF(v.y & 0xffff0000u);
  }
  uint2 o;
  o.x = ((u32)f2bf(a1)<<16) | f2bf(a0);
  o.y = ((u32)f2bf(a3)<<16) | f2bf(a2);
  *(uint2*)(Arow + (lane<<2)) = o;
}

// layer-0 shared aggregate
__global__ __launch_bounds__(256) void agg0_k(const u16* __restrict__ H,
    u16* __restrict__ A, const int* __restrict__ row_ptr,
    const int* __restrict__ csr_src, int N){
  int node = blockIdx.x*4 + (threadIdx.x>>6);
  if (node >= N) return;
  int lane = threadIdx.x & 63;
  agg_row(H, A + ((size_t)node<<8), row_ptr, csr_src, node, lane);
}

// layer-1 dense aggregate, expert->XCD pinned 1D grid (e = bid & (EZ-1))
__global__ __launch_bounds__(256) void agg1g_k(const u16* __restrict__ Hsrc,
    u16* __restrict__ Aout, const int* __restrict__ row_ptr,
    const int* __restrict__ csr_src, int N, int ezMask, int ezShift){
  int bid = blockIdx.x;
  int el = bid & ezMask;
  int xb = bid >> ezShift;
  int node = xb*4 + (threadIdx.x>>6);
  if (node >= N) return;
  int lane = threadIdx.x & 63;
  size_t NS = (size_t)N*DH;
  agg_row(Hsrc + (size_t)el*NS, Aout + (size_t)el*NS + ((size_t)node<<8),
          row_ptr, csr_src, node, lane);
}

// sparse (routed-rows) aggregate + root compaction, group-local
__global__ __launch_bounds__(256) void agg2sg_k(const u16* __restrict__ Hsrc,
    u16* __restrict__ Aout, u16* __restrict__ Rout,
    const int* __restrict__ row_ptr, const int* __restrict__ csr_src,
    const int* __restrict__ plist, const int* __restrict__ cnt,
    int N, int gBase){
  int el = blockIdx.y;
  int idx = blockIdx.x*4 + (threadIdx.x>>6);
  if (idx >= cnt[gBase + el]) return;
  int node = plist[(size_t)(gBase + el)*N + idx];
  size_t NS = (size_t)N*DH;
  const u16* H = Hsrc + (size_t)el*NS;
  int lane = threadIdx.x & 63;
  uint2 rootv = *(const uint2*)(H + ((size_t)node<<8) + (lane<<2));
  agg_row(H, Aout + (size_t)el*NS + ((size_t)idx<<8), row_ptr, csr_src, node, lane);
  *(uint2*)(Rout + (size_t)el*NS + ((size_t)idx<<8) + (lane<<2)) = rootv;
}

// ---------------- GEMM device body (m97 structure + swizzled LDS) ----------
__device__ __forceinline__ void gemm_dense_body(
    const u16* __restrict__ aBase, const u16* __restrict__ rBase,
    const u16* __restrict__ wBase, const float* __restrict__ be,
    u16* __restrict__ Oe, int N, int relu_flag, u16* As, u16* Bs)
{
  int tid = threadIdx.x;
  int lane = tid & 63, w = tid >> 6;
  int wr = w >> 1, wc = w & 1;
  int m0 = blockIdx.x * 128;
  int n0 = blockIdx.y * 128;

  int lrow = lane >> 2;
  int q8   = (((lane & 3) ^ ((lane >> 3) & 3))) * 8;
  int r0 = w*16 + lrow;
  int r1 = (w+4)*16 + lrow;
  int arow0 = m0 + r0; if (arow0 >= N) arow0 = N-1;
  int arow1 = m0 + r1; if (arow1 >= N) arow1 = N-1;
  long long aoff0 = (long long)arow0*256 + q8;
  long long aoff1 = (long long)arow1*256 + q8;
  long long boff0 = (long long)(n0 + r0)*512 + q8;
  long long boff1 = (long long)(n0 + r1)*512 + q8;
  u16* aL0 = As + (size_t)w*512;
  u16* aL1 = As + (size_t)(w+4)*512;
  u16* bL0 = Bs + (size_t)w*512;
  u16* bL1 = Bs + (size_t)(w+4)*512;

  f32x4 acc[4][4];
  #pragma unroll
  for (int a=0;a<4;a++)
    #pragma unroll
    for (int b=0;b<4;b++) acc[a][b] = (f32x4){0.f,0.f,0.f,0.f};

  int fr = lane & 15;
  int fk = (((lane >> 4) ^ ((fr >> 1) & 3))) * 8;
  const u16* aRead = As + (size_t)(wr*64 + fr)*32 + fk;
  const u16* bRead = Bs + (size_t)(wc*64 + fr)*32 + fk;

  #pragma unroll 1
  for (int half=0; half<2; ++half){
    const u16* sA = half ? rBase : aBase;
    #pragma unroll 1
    for (int kk=0; kk<8; ++kk){
      int kin = kk*32;
      int kg  = half*256 + kin;
      GLOAD_LDS16(sA + aoff0 + kin, aL0);
      GLOAD_LDS16(sA + aoff1 + kin, aL1);
      GLOAD_LDS16(wBase + boff0 + kg, bL0);
      GLOAD_LDS16(wBase + boff1 + kg, bL1);
      __syncthreads();
      s16x8 af[4], bf[4];
      #pragma unroll
      for (int mi=0;mi<4;mi++) af[mi] = *(const s16x8*)(aRead + mi*16*32);
      #pragma unroll
      for (int ni=0;ni<4;ni++) bf[ni] = *(const s16x8*)(bRead + ni*16*32);
      #pragma unroll
      for (int mi=0;mi<4;mi++)
        #pragma unroll
        for (int ni=0;ni<4;ni++)
          acc[mi][ni] = __builtin_amdgcn_mfma_f32_16x16x32_bf16(af[mi], bf[ni], acc[mi][ni], 0, 0, 0);
      __syncthreads();
    }
  }
  int fq = lane >> 4;
  #pragma unroll
  for (int ni=0;ni<4;ni++){
    int col = n0 + wc*64 + ni*16 + fr;
    float bv = be[col];
    #pragma unroll
    for (int mi=0;mi<4;mi++){
      int rowb = m0 + wr*64 + mi*16 + fq*4;
      f32x4 v = acc[mi][ni];
      #pragma unroll
      for (int j=0;j<4;j++){
        int row = rowb + j;
        if (row < N){
          float o = v[j] + bv;
          if (relu_flag) o = fmaxf(o, 0.f);
          Oe[(size_t)row*DH + col] = f2bf(o);
        }
      }
    }
  }
}

// layer-0: shared A0/bh, per-(group)expert W
__global__ __launch_bounds__(256,2) void gemm0g_k(
    const u16* __restrict__ A0, const u16* __restrict__ bh,
    const u16* __restrict__ WT, const float* __restrict__ bias,
    u16* __restrict__ Hout, int N){
  __shared__ u16 As[128*32];
  __shared__ u16 Bs[128*32];
  int el = blockIdx.z;
  gemm_dense_body(A0, bh, WT + (size_t)el*(256*512), bias + el*256,
                  Hout + (size_t)el*((size_t)N*DH), N, 1, As, Bs);
}
// layer-1: per-expert A/H/W
__global__ __launch_bounds__(256,2) void gemm1g_k(
    const u16* __restrict__ Aagg, const u16* __restrict__ Hroot,
    const u16* __restrict__ WT, const float* __restrict__ bias,
    u16* __restrict__ Hout, int N){
  __shared__ u16 As[128*32];
  __shared__ u16 Bs[128*32];
  int el = blockIdx.z;
  size_t NS = (size_t)N*DH;
  gemm_dense_body(Aagg + (size_t)el*NS, Hroot + (size_t)el*NS,
                  WT + (size_t)el*(256*512), bias + el*256,
                  Hout + (size_t)el*NS, N, 1, As, Bs);
}

// sparse layer-2 GEMM: compacted linear A and root, group-local
__global__ __launch_bounds__(256,2) void gemm2sg_k(
    const u16* __restrict__ Aagg, const u16* __restrict__ Rc,
    const u16* __restrict__ WT, const float* __restrict__ bias,
    u16* __restrict__ Hout, const int* __restrict__ cnte, int N, int gBase)
{
  __shared__ u16 As[128*32];
  __shared__ u16 Bs[128*32];
  int el = blockIdx.z;
  int cnt = cnte[gBase + el];
  int m0 = blockIdx.x * 128;
  if (m0 >= cnt) return;
  size_t NS = (size_t)N*DH;
  const u16* aBase = Aagg + (size_t)el*NS;
  const u16* rBase = Rc + (size_t)el*NS;
  const u16* wBase = WT + (size_t)el*(256*512);
  const float* be  = bias + el*256;
  u16* Oe = Hout + (size_t)el*NS;

  int tid = threadIdx.x;
  int lane = tid & 63, w = tid >> 6;
  int wr = w >> 1, wc = w & 1;
  int n0 = blockIdx.y * 128;

  int lrow = lane >> 2;
  int q8   = (((lane & 3) ^ ((lane >> 3) & 3))) * 8;
  int r0 = w*16 + lrow;
  int r1 = (w+4)*16 + lrow;
  int ai0 = m0 + r0; if (ai0 >= cnt) ai0 = cnt-1;
  int ai1 = m0 + r1; if (ai1 >= cnt) ai1 = cnt-1;
  long long aoff0 = (long long)ai0*256 + q8;
  long long aoff1 = (long long)ai1*256 + q8;
  long long boff0 = (long long)(n0 + r0)*512 + q8;
  long long boff1 = (long long)(n0 + r1)*512 + q8;
  u16* aL0 = As + (size_t)w*512;
  u16* aL1 = As + (size_t)(w+4)*512;
  u16* bL0 = Bs + (size_t)w*512;
  u16* bL1 = Bs + (size_t)(w+4)*512;

  f32x4 acc[4][4];
  #pragma unroll
  for (int a=0;a<4;a++)
    #pragma unroll
    for (int b=0;b<4;b++) acc[a][b] = (f32x4){0.f,0.f,0.f,0.f};

  int fr = lane & 15;
  int fk = (((lane >> 4) ^ ((fr >> 1) & 3))) * 8;
  const u16* aRead = As + (size_t)(wr*64 + fr)*32 + fk;
  const u16* bRead = Bs + (size_t)(wc*64 + fr)*32 + fk;

  #pragma unroll 1
  for (int half=0; half<2; ++half){
    const u16* sA = half ? rBase : aBase;
    #pragma unroll 1
    for (int kk=0; kk<8; ++kk){
      int kin = kk*32;
      int kg  = half*256 + kin;
      GLOAD_LDS16(sA + aoff0 + kin, aL0);
      GLOAD_LDS16(sA + aoff1 + kin, aL1);
      GLOAD_LDS16(wBase + boff0 + kg, bL0);
      GLOAD_LDS16(wBase + boff1 + kg, bL1);
      __syncthreads();
      s16x8 af[4], bf[4];
      #pragma unroll
      for (int mi=0;mi<4;mi++) af[mi] = *(const s16x8*)(aRead + mi*16*32);
      #pragma unroll
      for (int ni=0;ni<4;ni++) bf[ni] = *(const s16x8*)(bRead + ni*16*32);
      #pragma unroll
      for (int mi=0;mi<4;mi++)
        #pragma unroll
        for (int ni=0;ni<4;ni++)
          acc[mi][ni] = __builtin_amdgcn_mfma_f32_16x16x32_bf16(af[mi], bf[ni], acc[mi][ni], 0, 0, 0);
      __syncthreads();
    }
  }
  int fq = lane >> 4;
  #pragma unroll
  for (int ni=0;ni<4;ni++){
    int col = n0 + wc*64 + ni*16 + fr;
    float bv = be[col];
    #pragma unroll
    for (int mi=0;mi<4;mi++){
      int rowb = m0 + wr*64 + mi*16 + fq*4;
      f32x4 v = acc[mi][ni];
      #pragma unroll
      for (int j=0;j<4;j++){
        int row = rowb + j;
        if (row < cnt){
          float o = v[j] + bv;
          Oe[(size_t)row*DH + col] = f2bf(o);
        }
      }
    }
  }
}

// ---------------- combine (group-local sparse, write/accumulate) -----------
__global__ __launch_bounds__(256) void combine_spg_k(const u16* __restrict__ H3c,
    const int* __restrict__ ridx, const int* __restrict__ ppos,
    const float* __restrict__ rval, float* __restrict__ out,
    int N, int gBase, int ezCnt, int first){
  int n = blockIdx.x; if (n>=N) return;
  int f = threadIdx.x;
  size_t NS = (size_t)N*DH;
  size_t off = (size_t)n*DH + f;
  float acc = first ? 0.f : out[off];
  #pragma unroll
  for (int p=0;p<2;p++){
    int el = ridx[n*2+p] - gBase;
    if (el >= 0 && el < ezCnt)
      acc += rval[n*2+p] * bitsToF(((u32)H3c[(size_t)el*NS + (size_t)ppos[n*2+p]*DH + f])<<16);
  }
  out[off] = acc;
}

extern "C" void kernel_launch(void* const* d_in, const int* in_sizes, int n_in,
                              void* d_out, int out_size, void* d_ws, size_t ws_size,
                              hipStream_t stream)
{
  const float* x    = (const float*)d_in[0];
  const int*   ei   = (const int*)d_in[1];
  const int*   batch= (const int*)d_in[2];
  const float* encW = (const float*)d_in[3];
  const float* encb = (const float*)d_in[4];
  const float* rW1  = (const float*)d_in[5];
  const float* rb1  = (const float*)d_in[6];
  const float* rW2  = (const float*)d_in[7];
  const float* rb2  = (const float*)d_in[8];
  const float* Wrel = (const float*)d_in[9];
  const float* brel = (const float*)d_in[10];
  const float* Wroot= (const float*)d_in[11];
  int N = in_sizes[2];
  int E = in_sizes[1]/2;
  float* out = (float*)d_out;
  (void)n_in; (void)out_size;

  size_t NS = (size_t)N*DH;
  char* p = (char*)d_ws;
  auto carve = [&](size_t bytes)->char*{
    char* r = p; p += (bytes + 255) & ~(size_t)255; return r;
  };
  u16*  bh   = (u16*)carve(NS*2);
  u16*  WT   = (u16*)carve((size_t)3*NEXP*256*512*2);
  int*  deg  = (int*)carve((size_t)N*4 + 64*4);
  int*  ng   = deg + N;
  int*  eg   = ng + GNUM;
  int*  row_ptr = (int*)carve(((size_t)N+1)*4);
  int*  cursor  = (int*)carve((size_t)N*4);
  int*  csr     = (int*)carve((size_t)E*4);
  float* sizef  = (float*)carve(GNUM*2*4);
  int*  ridx    = (int*)carve((size_t)N*2*4);
  float* rvalv  = (float*)carve((size_t)N*2*4);
  int*  ecnt    = (int*)carve(NEXP*4);
  int*  plist   = (int*)carve((size_t)NEXP*N*4);
  int*  ppos    = (int*)carve((size_t)N*2*4);
  u16*  A0      = (u16*)carve(NS*2);
  size_t baseUsed = (size_t)(p - (char*)d_ws);

  int EZ = 0;
  for (int cand = NEXP; cand >= 1; cand >>= 1){
    if (baseUsed + (size_t)cand*3*NS*2 <= ws_size){ EZ = cand; break; }
  }
  if (EZ == 0){ mark_fail_k<<<1,1,0,stream>>>(out); return; }
  int ezShift = (EZ==8)?3 : (EZ==4)?2 : (EZ==2)?1 : 0;

  u16* Abuf = (u16*)carve((size_t)EZ*NS*2);   // dense A1 / compact A2
  u16* Hc   = (u16*)carve((size_t)EZ*NS*2);   // H1 / compact root
  u16* Hn   = (u16*)carve((size_t)EZ*NS*2);   // H2 / compact H3
  float* hf; float* rh;
  if (EZ >= 2){ hf = (float*)Abuf; rh = (float*)Hn; }
  else {
    hf = (float*)carve(NS*4);
    rh = (float*)carve(NS*4);
    if ((size_t)(p - (char*)d_ws) > ws_size){ mark_fail_k<<<1,1,0,stream>>>(out); return; }
  }

  hipMemsetAsync(deg, 0, (size_t)N*4 + (size_t)2*GNUM*4, stream);
  hipMemsetAsync(ecnt, 0, NEXP*4, stream);

  int eb = (E + 255)/256;
  count_edges_k<<<eb, 256, 0, stream>>>(ei, batch, deg, eg, E);
  count_nodes_k<<<(N+255)/256, 256, 0, stream>>>(batch, ng, N);
  scan_deg_k<<<1, SCAN_T, 0, stream>>>(deg, row_ptr, cursor, N);
  scatter_edges_k<<<eb, 256, 0, stream>>>(ei, cursor, csr, E);
  size_feats_k<<<1, 64, 0, stream>>>(ng, eg, sizef);
  encoder_k<<<N, 256, 0, stream>>>(x, encW, encb, hf, bh, N);
  convw_k<<<dim3(16,2,3*NEXP), dim3(64,4), 0, stream>>>(Wrel, Wroot, WT);
  router1_k<<<(N+R1N-1)/R1N, 256, 0, stream>>>(hf, sizef, batch, rW1, rb1, rh, N);
  router2_k<<<(N+3)/4, 256, 0, stream>>>(rh, rW2, rb2, ridx, rvalv, N);
  rsort_k<<<(N+255)/256, 256, 0, stream>>>(ridx, ecnt, plist, ppos, N);

  int aggx = (N+3)/4;
  int mt = (N+127)/128;
  const size_t WE = (size_t)256*512;

  agg0_k<<<aggx, 256, 0, stream>>>(bh, A0, row_ptr, csr, N);

  for (int g = 0; g < NEXP; g += EZ){
    // layer 0 (dense): A0/bh shared, per-expert W -> Hc (H1)
    gemm0g_k<<<dim3(mt,2,EZ), 256, 0, stream>>>(A0, bh,
        WT + ((size_t)0*NEXP + g)*WE, brel + (0*NEXP + g)*256, Hc, N);
    // layer 1 (dense): XCD-pinned aggregate Hc -> Abuf, then GEMM -> Hn (H2)
    agg1g_k<<<aggx*EZ, 256, 0, stream>>>(Hc, Abuf, row_ptr, csr, N, EZ-1, ezShift);
    gemm1g_k<<<dim3(mt,2,EZ), 256, 0, stream>>>(Abuf, Hc,
        WT + ((size_t)1*NEXP + g)*WE, brel + (1*NEXP + g)*256, Hn, N);
    // layer 2 (routing-sparse): compact agg Hn -> Abuf, root -> Hc (dead H1);
    // GEMM -> Hn compact (dense H2 consumed by agg2sg; stream-ordered)
    agg2sg_k<<<dim3(aggx,EZ), 256, 0, stream>>>(Hn, Abuf, Hc, row_ptr, csr,
        plist, ecnt, N, g);
    gemm2sg_k<<<dim3(mt,2,EZ), 256, 0, stream>>>(Abuf, Hc,
        WT + ((size_t)2*NEXP + g)*WE, brel + (2*NEXP + g)*256, Hn, ecnt, N, g);
    // routed combine (write on first group, accumulate after)
    combine_spg_k<<<N, 256, 0, stream>>>(Hn, ridx, ppos, rvalv, out, N, g, EZ, g==0);
  }
}